// Round 1
// baseline (840.198 us; speedup 1.0000x reference)
//
#include <hip/hip_runtime.h>

#define N_NODES 50000
#define N_EDGES 800000
#define IN_DIM 32
#define HD 256   // H*D
#define H_ 8
#define D_ 32
#define TM 32    // nodes per block in gemm1

// ---------------- CSR build ----------------

__global__ void k_hist(const int* __restrict__ dst, int* __restrict__ deg){
  int e = blockIdx.x*256+threadIdx.x;
  if (e < N_EDGES) atomicAdd(&deg[dst[e]], 1);
}

__global__ void k_block_sums(const int* __restrict__ deg, int* __restrict__ bsums){
  int i = blockIdx.x*256+threadIdx.x;
  int v = (i<N_NODES)? deg[i]:0;
  #pragma unroll
  for (int o=32;o>=1;o>>=1) v += __shfl_xor(v,o,64);
  __shared__ int ws[4];
  if ((threadIdx.x&63)==0) ws[threadIdx.x>>6]=v;
  __syncthreads();
  if (threadIdx.x==0) bsums[blockIdx.x]=ws[0]+ws[1]+ws[2]+ws[3];
}

__global__ void k_scan_bsums(int* bsums, int nb){
  if (threadIdx.x==0 && blockIdx.x==0){
    int a=0;
    for (int i=0;i<nb;i++){int t=bsums[i]; bsums[i]=a; a+=t;}
  }
}

__device__ inline int wave_incl_scan(int v){
  int lane = threadIdx.x & 63;
  #pragma unroll
  for (int o=1;o<64;o<<=1){
    int t = __shfl_up(v,o,64);
    if (lane>=o) v+=t;
  }
  return v;
}

__global__ void k_scan_chunks(const int* __restrict__ deg, const int* __restrict__ bsums,
                              int* __restrict__ offs, int* __restrict__ cursor){
  int i = blockIdx.x*256+threadIdx.x;
  int v = (i<N_NODES)? deg[i]:0;
  int incl = wave_incl_scan(v);
  __shared__ int ws[4];
  int wid=threadIdx.x>>6, lane=threadIdx.x&63;
  if (lane==63) ws[wid]=incl;
  __syncthreads();
  if (threadIdx.x==0){int a=0; for(int w=0;w<4;w++){int t=ws[w];ws[w]=a;a+=t;}}
  __syncthreads();
  int excl = incl - v + ws[wid] + bsums[blockIdx.x];
  if (i<N_NODES){ offs[i]=excl; cursor[i]=excl; }
  if (i==N_NODES-1) offs[N_NODES]=excl+v;
}

__global__ void k_scatter(const int* __restrict__ src, const int* __restrict__ dst,
                          int* __restrict__ cursor, int* __restrict__ csr_src,
                          int* __restrict__ csr_eid){
  int e = blockIdx.x*256+threadIdx.x;
  if (e<N_EDGES){
    int d = dst[e];
    int pos = atomicAdd(&cursor[d],1);
    csr_src[pos]=src[e];
    csr_eid[pos]=e;
  }
}

// ---------------- layer 0 GEMM (+ el/er) ----------------
// one block per node; thread j computes feat[n][j]; shfl-reduce per 32-lane head group

__global__ __launch_bounds__(256) void k_gemm0(const float* __restrict__ h, const float* __restrict__ W0,
   const float* __restrict__ al, const float* __restrict__ ar,
   float* __restrict__ feat, float* __restrict__ el, float* __restrict__ er){
  int n = blockIdx.x, tid=threadIdx.x;
  __shared__ float hrow[IN_DIM];
  if (tid<IN_DIM) hrow[tid]=h[n*IN_DIM+tid];
  __syncthreads();
  float acc=0.f;
  #pragma unroll
  for (int k=0;k<IN_DIM;k++) acc = fmaf(hrow[k], W0[k*HD+tid], acc);
  feat[n*HD+tid]=acc;
  int sub = tid&31;
  float pl = acc*al[tid], pr = acc*ar[tid];
  #pragma unroll
  for (int o=16;o>=1;o>>=1){ pl+=__shfl_xor(pl,o,64); pr+=__shfl_xor(pr,o,64); }
  if (sub==0){ int head=tid>>5; el[n*H_+head]=pl; er[n*H_+head]=pr; }
}

// ---------------- layer 1 GEMM (+ el/er) ----------------
// 32-node M-tile in LDS; thread = 8 cols x 4 nodes

__global__ __launch_bounds__(256) void k_gemm1(const float* __restrict__ x, const float* __restrict__ W,
   const float* __restrict__ al, const float* __restrict__ ar,
   float* __restrict__ feat, float* __restrict__ el, float* __restrict__ er){
  __shared__ float xs[HD][TM+4];   // pad 4 keeps float4 alignment (stride 144B) and breaks bank aliasing
  int tid=threadIdx.x;
  int nb = blockIdx.x*TM;
  for (int i=0;i<TM;i++){
    int node = nb+i;
    xs[tid][i] = (node<N_NODES)? x[node*HD+tid] : 0.f;
  }
  __syncthreads();
  int c0 = tid&31;          // dim within head; cols c0+32*c
  int nl0 = (tid>>5)*4;     // 4 consecutive local nodes
  float acc[8][4];
  #pragma unroll
  for(int c=0;c<8;c++)
    #pragma unroll
    for(int nn=0;nn<4;nn++) acc[c][nn]=0.f;
  #pragma unroll 2
  for (int k=0;k<HD;k++){
    float4 xv = *(const float4*)&xs[k][nl0];
    float w[8];
    #pragma unroll
    for(int c=0;c<8;c++) w[c]=W[k*HD + c0 + 32*c];
    #pragma unroll
    for(int c=0;c<8;c++){
      acc[c][0]=fmaf(w[c],xv.x,acc[c][0]);
      acc[c][1]=fmaf(w[c],xv.y,acc[c][1]);
      acc[c][2]=fmaf(w[c],xv.z,acc[c][2]);
      acc[c][3]=fmaf(w[c],xv.w,acc[c][3]);
    }
  }
  #pragma unroll
  for (int nn=0;nn<4;nn++){
    int node = nb+nl0+nn;
    if (node<N_NODES){
      #pragma unroll
      for(int c=0;c<8;c++) feat[(size_t)node*HD + c0+32*c] = acc[c][nn];
    }
  }
  // el/er: col (c0+32c) -> head c, dim c0; reduce over the 32-lane group
  #pragma unroll
  for (int nn=0;nn<4;nn++){
    int node = nb+nl0+nn;
    #pragma unroll
    for (int c=0;c<8;c++){
      float pl = acc[c][nn]*al[c*32+c0];
      float pr = acc[c][nn]*ar[c*32+c0];
      #pragma unroll
      for(int o=16;o>=1;o>>=1){ pl+=__shfl_xor(pl,o,64); pr+=__shfl_xor(pr,o,64); }
      if (c0==0 && node<N_NODES){ el[node*H_+c]=pl; er[node*H_+c]=pr; }
    }
  }
}

// ---------------- edge softmax + aggregate ----------------
// one block per dst node; thread = (head = tid>>5, dim/sub = tid&31)

template<int LAYER>
__global__ __launch_bounds__(256) void k_agg(const int* __restrict__ offs, const int* __restrict__ csr_src,
   const int* __restrict__ csr_eid, const float* __restrict__ feat,
   const float* __restrict__ el, const float* __restrict__ er, const float* __restrict__ bias,
   float* __restrict__ out, float* __restrict__ alpha_out){
  int n = blockIdx.x, tid=threadIdx.x;
  int head=tid>>5, sub=tid&31;
  int off = offs[n], deg = offs[n+1]-off;
  float er_n = er[n*H_+head];
  // phase 1: online (m,s) per head, 32 lanes strided over edges
  float m=-1e30f, s=0.f;
  for (int i=sub;i<deg;i+=32){
    int sn = csr_src[off+i];
    float sc = el[sn*H_+head]+er_n;
    sc = sc>0.f? sc : 0.2f*sc;
    float mn = fmaxf(m,sc);
    s = s*__expf(m-mn) + __expf(sc-mn);
    m = mn;
  }
  #pragma unroll
  for (int o=16;o>=1;o>>=1){
    float m2=__shfl_xor(m,o,64), s2=__shfl_xor(s,o,64);
    float mn=fmaxf(m,m2);
    s = s*__expf(m-mn) + s2*__expf(m2-mn);
    m = mn;
  }
  float inv_s = (deg>0) ? 1.f/s : 0.f;
  // phase 2: alpha-weighted accumulation, coalesced feat[src] reads
  float acc=0.f;
  for (int i=0;i<deg;i++){
    int sn = csr_src[off+i];
    float sc = el[sn*H_+head]+er_n;
    sc = sc>0.f? sc : 0.2f*sc;
    float a = __expf(sc-m)*inv_s;
    acc = fmaf(a, feat[(size_t)sn*HD+tid], acc);
    if (LAYER==1 && sub==0) alpha_out[(size_t)csr_eid[off+i]*H_+head]=a;
  }
  if (LAYER==0){
    out[(size_t)n*HD+tid] = fmaxf(acc + bias[tid], 0.f);     // fused bias + ReLU -> h1
  } else {
    __shared__ float red[256];
    red[tid] = acc + bias[tid];
    __syncthreads();
    if (tid<D_){
      float sum=0.f;
      #pragma unroll
      for(int hh=0;hh<H_;hh++) sum+=red[hh*D_+tid];
      out[(size_t)n*D_+tid]=sum*0.125f;                      // fused head-mean
    }
  }
}

// ---------------- launcher ----------------

extern "C" void kernel_launch(void* const* d_in, const int* in_sizes, int n_in,
                              void* d_out, int out_size, void* d_ws, size_t ws_size,
                              hipStream_t stream){
  const float* h   = (const float*)d_in[0];
  const int*   src = (const int*)d_in[1];
  const int*   dst = (const int*)d_in[2];
  const float* W0  = (const float*)d_in[3];
  const float* al0 = (const float*)d_in[4];
  const float* ar0 = (const float*)d_in[5];
  const float* b0  = (const float*)d_in[6];
  const float* W1  = (const float*)d_in[7];
  const float* al1 = (const float*)d_in[8];
  const float* ar1 = (const float*)d_in[9];
  const float* b1  = (const float*)d_in[10];
  float* out_final = (float*)d_out;                    // N*32
  float* alpha_out = (float*)d_out + (size_t)N_NODES*D_; // E*8

  char* wsp = (char*)d_ws;
  auto alloc=[&](size_t bytes)->char*{ char* p=wsp; wsp += (bytes+255)&~size_t(255); return p; };
  int*   deg     = (int*)alloc((size_t)N_NODES*4);
  int*   offs    = (int*)alloc((size_t)(N_NODES+1)*4);
  int*   cursor  = (int*)alloc((size_t)N_NODES*4);
  int*   bsums   = (int*)alloc(1024);
  int*   csr_src = (int*)alloc((size_t)N_EDGES*4);
  int*   csr_eid = (int*)alloc((size_t)N_EDGES*4);
  float* feat    = (float*)alloc((size_t)N_NODES*HD*4);
  float* h1      = (float*)alloc((size_t)N_NODES*HD*4);
  float* el      = (float*)alloc((size_t)N_NODES*H_*4);
  float* er      = (float*)alloc((size_t)N_NODES*H_*4);

  hipMemsetAsync(deg, 0, (size_t)N_NODES*4, stream);
  int eb = (N_EDGES+255)/256;
  int nbchunks = (N_NODES+255)/256;
  k_hist       <<<eb,      256,0,stream>>>(dst, deg);
  k_block_sums <<<nbchunks,256,0,stream>>>(deg, bsums);
  k_scan_bsums <<<1,       64, 0,stream>>>(bsums, nbchunks);
  k_scan_chunks<<<nbchunks,256,0,stream>>>(deg, bsums, offs, cursor);
  k_scatter    <<<eb,      256,0,stream>>>(src, dst, cursor, csr_src, csr_eid);

  k_gemm0<<<N_NODES,256,0,stream>>>(h, W0, al0, ar0, feat, el, er);
  k_agg<0><<<N_NODES,256,0,stream>>>(offs, csr_src, csr_eid, feat, el, er, b0, h1, nullptr);
  k_gemm1<<<(N_NODES+TM-1)/TM,256,0,stream>>>(h1, W1, al1, ar1, feat, el, er);
  k_agg<1><<<N_NODES,256,0,stream>>>(offs, csr_src, csr_eid, feat, el, er, b1, out_final, alpha_out);
}

// Round 2
// 650.103 us; speedup vs baseline: 1.2924x; 1.2924x over previous
//
#include <hip/hip_runtime.h>

#define N_NODES 50000
#define N_EDGES 800000
#define IN_DIM 32
#define HD 256   // H*D
#define H_ 8
#define D_ 32
#define TM 32    // nodes per block in gemm1

// ---------------- CSR build ----------------

__global__ void k_hist(const int* __restrict__ dst, int* __restrict__ deg){
  int e = blockIdx.x*256+threadIdx.x;
  if (e < N_EDGES) atomicAdd(&deg[dst[e]], 1);
}

__global__ void k_block_sums(const int* __restrict__ deg, int* __restrict__ bsums){
  int i = blockIdx.x*256+threadIdx.x;
  int v = (i<N_NODES)? deg[i]:0;
  #pragma unroll
  for (int o=32;o>=1;o>>=1) v += __shfl_xor(v,o,64);
  __shared__ int ws[4];
  if ((threadIdx.x&63)==0) ws[threadIdx.x>>6]=v;
  __syncthreads();
  if (threadIdx.x==0) bsums[blockIdx.x]=ws[0]+ws[1]+ws[2]+ws[3];
}

__global__ void k_scan_bsums(int* bsums, int nb){
  if (threadIdx.x==0 && blockIdx.x==0){
    int a=0;
    for (int i=0;i<nb;i++){int t=bsums[i]; bsums[i]=a; a+=t;}
  }
}

__device__ inline int wave_incl_scan(int v){
  int lane = threadIdx.x & 63;
  #pragma unroll
  for (int o=1;o<64;o<<=1){
    int t = __shfl_up(v,o,64);
    if (lane>=o) v+=t;
  }
  return v;
}

__global__ void k_scan_chunks(const int* __restrict__ deg, const int* __restrict__ bsums,
                              int* __restrict__ offs, int* __restrict__ cursor){
  int i = blockIdx.x*256+threadIdx.x;
  int v = (i<N_NODES)? deg[i]:0;
  int incl = wave_incl_scan(v);
  __shared__ int ws[4];
  int wid=threadIdx.x>>6, lane=threadIdx.x&63;
  if (lane==63) ws[wid]=incl;
  __syncthreads();
  if (threadIdx.x==0){int a=0; for(int w=0;w<4;w++){int t=ws[w];ws[w]=a;a+=t;}}
  __syncthreads();
  int excl = incl - v + ws[wid] + bsums[blockIdx.x];
  if (i<N_NODES){ offs[i]=excl; cursor[i]=excl; }
  if (i==N_NODES-1) offs[N_NODES]=excl+v;
}

__global__ void k_scatter(const int* __restrict__ src, const int* __restrict__ dst,
                          int* __restrict__ cursor, int* __restrict__ csr_src,
                          int* __restrict__ csr_eid){
  int e = blockIdx.x*256+threadIdx.x;
  if (e<N_EDGES){
    int d = dst[e];
    int pos = atomicAdd(&cursor[d],1);
    csr_src[pos]=src[e];
    csr_eid[pos]=e;
  }
}

// ---------------- layer 0 GEMM (+ el/er) ----------------

__global__ __launch_bounds__(256) void k_gemm0(const float* __restrict__ h, const float* __restrict__ W0,
   const float* __restrict__ al, const float* __restrict__ ar,
   float* __restrict__ feat, float* __restrict__ el, float* __restrict__ er){
  int n = blockIdx.x, tid=threadIdx.x;
  __shared__ float hrow[IN_DIM];
  if (tid<IN_DIM) hrow[tid]=h[n*IN_DIM+tid];
  __syncthreads();
  float acc=0.f;
  #pragma unroll
  for (int k=0;k<IN_DIM;k++) acc = fmaf(hrow[k], W0[k*HD+tid], acc);
  feat[n*HD+tid]=acc;
  int sub = tid&31;
  float pl = acc*al[tid], pr = acc*ar[tid];
  #pragma unroll
  for (int o=16;o>=1;o>>=1){ pl+=__shfl_xor(pl,o,64); pr+=__shfl_xor(pr,o,64); }
  if (sub==0){ int head=tid>>5; el[n*H_+head]=pl; er[n*H_+head]=pr; }
}

// ---------------- layer 1 GEMM (+ el/er) ----------------

__global__ __launch_bounds__(256) void k_gemm1(const float* __restrict__ x, const float* __restrict__ W,
   const float* __restrict__ al, const float* __restrict__ ar,
   float* __restrict__ feat, float* __restrict__ el, float* __restrict__ er){
  __shared__ float xs[HD][TM+4];
  int tid=threadIdx.x;
  int nb = blockIdx.x*TM;
  for (int i=0;i<TM;i++){
    int node = nb+i;
    xs[tid][i] = (node<N_NODES)? x[node*HD+tid] : 0.f;
  }
  __syncthreads();
  int c0 = tid&31;
  int nl0 = (tid>>5)*4;
  float acc[8][4];
  #pragma unroll
  for(int c=0;c<8;c++)
    #pragma unroll
    for(int nn=0;nn<4;nn++) acc[c][nn]=0.f;
  #pragma unroll 2
  for (int k=0;k<HD;k++){
    float4 xv = *(const float4*)&xs[k][nl0];
    float w[8];
    #pragma unroll
    for(int c=0;c<8;c++) w[c]=W[k*HD + c0 + 32*c];
    #pragma unroll
    for(int c=0;c<8;c++){
      acc[c][0]=fmaf(w[c],xv.x,acc[c][0]);
      acc[c][1]=fmaf(w[c],xv.y,acc[c][1]);
      acc[c][2]=fmaf(w[c],xv.z,acc[c][2]);
      acc[c][3]=fmaf(w[c],xv.w,acc[c][3]);
    }
  }
  #pragma unroll
  for (int nn=0;nn<4;nn++){
    int node = nb+nl0+nn;
    if (node<N_NODES){
      #pragma unroll
      for(int c=0;c<8;c++) feat[(size_t)node*HD + c0+32*c] = acc[c][nn];
    }
  }
  #pragma unroll
  for (int nn=0;nn<4;nn++){
    int node = nb+nl0+nn;
    #pragma unroll
    for (int c=0;c<8;c++){
      float pl = acc[c][nn]*al[c*32+c0];
      float pr = acc[c][nn]*ar[c*32+c0];
      #pragma unroll
      for(int o=16;o>=1;o>>=1){ pl+=__shfl_xor(pl,o,64); pr+=__shfl_xor(pr,o,64); }
      if (c0==0 && node<N_NODES){ el[node*H_+c]=pl; er[node*H_+c]=pr; }
    }
  }
}

// ---------------- edge softmax + aggregate ----------------
// phase 1: thread=(head=tid>>5, sub=tid&31), online (m,s) per head
// phase 2: wave w owns edges w, w+4, ...; lane l covers dims 4l..4l+3 (float4),
//          head = l>>3; whole 1KB feat row loaded by one global_load_dwordx4/wave

template<int LAYER>
__global__ __launch_bounds__(256) void k_agg(const int* __restrict__ offs, const int* __restrict__ csr_src,
   const int* __restrict__ csr_eid, const float* __restrict__ feat,
   const float* __restrict__ el, const float* __restrict__ er, const float* __restrict__ bias,
   float* __restrict__ out, float* __restrict__ alpha_out){
  int n = blockIdx.x, tid=threadIdx.x;
  int off = offs[n], deg = offs[n+1]-off;
  __shared__ float sm_m[H_], sm_s[H_];
  __shared__ float red[4][HD];

  { // phase 1
    int head=tid>>5, sub=tid&31;
    float er_n = er[n*H_+head];
    float m=-1e30f, s=0.f;
    for (int i=sub;i<deg;i+=32){
      int sn = csr_src[off+i];
      float sc = el[sn*H_+head]+er_n;
      sc = sc>0.f? sc : 0.2f*sc;
      float mn = fmaxf(m,sc);
      s = s*__expf(m-mn) + __expf(sc-mn);
      m = mn;
    }
    #pragma unroll
    for (int o=16;o>=1;o>>=1){
      float m2=__shfl_xor(m,o,64), s2=__shfl_xor(s,o,64);
      float mn=fmaxf(m,m2);
      s = s*__expf(m-mn) + s2*__expf(m2-mn);
      m = mn;
    }
    if (sub==0){ sm_m[head]=m; sm_s[head]=s; }
  }
  __syncthreads();

  // phase 2
  int wave = tid>>6, lane = tid&63;
  int head = lane>>3;                 // dims 4*lane..4*lane+3 all in head lane/8
  float m = sm_m[head];
  float s = sm_s[head];
  float inv_s = (s>0.f)? 1.f/s : 0.f;
  float er_n = er[n*H_+head];
  float4 acc = make_float4(0.f,0.f,0.f,0.f);
  for (int i=wave; i<deg; i+=4){
    int p = off+i;
    int sn = csr_src[p];
    float sc = el[sn*H_+head]+er_n;
    sc = sc>0.f? sc : 0.2f*sc;
    float a = __expf(sc-m)*inv_s;
    float4 fv = *(const float4*)&feat[(size_t)sn*HD + 4*lane];
    acc.x = fmaf(a,fv.x,acc.x);
    acc.y = fmaf(a,fv.y,acc.y);
    acc.z = fmaf(a,fv.z,acc.z);
    acc.w = fmaf(a,fv.w,acc.w);
    if (LAYER==1 && (lane&7)==0) alpha_out[(size_t)csr_eid[p]*H_+head]=a;
  }
  *(float4*)&red[wave][4*lane] = acc;
  __syncthreads();

  float v = red[0][tid]+red[1][tid]+red[2][tid]+red[3][tid] + bias[tid];
  if (LAYER==0){
    out[(size_t)n*HD+tid] = fmaxf(v, 0.f);                 // fused bias + ReLU -> h1
  } else {
    __syncthreads();
    red[0][tid]=v;
    __syncthreads();
    if (tid<D_){
      float sum=0.f;
      #pragma unroll
      for(int hh=0;hh<H_;hh++) sum+=red[0][hh*D_+tid];
      out[(size_t)n*D_+tid]=sum*0.125f;                    // fused head-mean
    }
  }
}

// ---------------- launcher ----------------

extern "C" void kernel_launch(void* const* d_in, const int* in_sizes, int n_in,
                              void* d_out, int out_size, void* d_ws, size_t ws_size,
                              hipStream_t stream){
  const float* h   = (const float*)d_in[0];
  const int*   src = (const int*)d_in[1];
  const int*   dst = (const int*)d_in[2];
  const float* W0  = (const float*)d_in[3];
  const float* al0 = (const float*)d_in[4];
  const float* ar0 = (const float*)d_in[5];
  const float* b0  = (const float*)d_in[6];
  const float* W1  = (const float*)d_in[7];
  const float* al1 = (const float*)d_in[8];
  const float* ar1 = (const float*)d_in[9];
  const float* b1  = (const float*)d_in[10];
  float* out_final = (float*)d_out;
  float* alpha_out = (float*)d_out + (size_t)N_NODES*D_;

  char* wsp = (char*)d_ws;
  auto alloc=[&](size_t bytes)->char*{ char* p=wsp; wsp += (bytes+255)&~size_t(255); return p; };
  int*   deg     = (int*)alloc((size_t)N_NODES*4);
  int*   offs    = (int*)alloc((size_t)(N_NODES+1)*4);
  int*   cursor  = (int*)alloc((size_t)N_NODES*4);
  int*   bsums   = (int*)alloc(1024);
  int*   csr_src = (int*)alloc((size_t)N_EDGES*4);
  int*   csr_eid = (int*)alloc((size_t)N_EDGES*4);
  float* feat    = (float*)alloc((size_t)N_NODES*HD*4);
  float* h1      = (float*)alloc((size_t)N_NODES*HD*4);
  float* el      = (float*)alloc((size_t)N_NODES*H_*4);
  float* er      = (float*)alloc((size_t)N_NODES*H_*4);

  hipMemsetAsync(deg, 0, (size_t)N_NODES*4, stream);
  int eb = (N_EDGES+255)/256;
  int nbchunks = (N_NODES+255)/256;
  k_hist       <<<eb,      256,0,stream>>>(dst, deg);
  k_block_sums <<<nbchunks,256,0,stream>>>(deg, bsums);
  k_scan_bsums <<<1,       64, 0,stream>>>(bsums, nbchunks);
  k_scan_chunks<<<nbchunks,256,0,stream>>>(deg, bsums, offs, cursor);
  k_scatter    <<<eb,      256,0,stream>>>(src, dst, cursor, csr_src, csr_eid);

  k_gemm0<<<N_NODES,256,0,stream>>>(h, W0, al0, ar0, feat, el, er);
  k_agg<0><<<N_NODES,256,0,stream>>>(offs, csr_src, csr_eid, feat, el, er, b0, h1, nullptr);
  k_gemm1<<<(N_NODES+TM-1)/TM,256,0,stream>>>(h1, W1, al1, ar1, feat, el, er);
  k_agg<1><<<N_NODES,256,0,stream>>>(offs, csr_src, csr_eid, feat, el, er, b1, out_final, alpha_out);
}

// Round 3
// 559.106 us; speedup vs baseline: 1.5028x; 1.1628x over previous
//
#include <hip/hip_runtime.h>

#define N_NODES 50000
#define N_EDGES 800000
#define IN_DIM 32
#define HD 256   // H*D
#define H_ 8
#define D_ 32
#define TM 32    // nodes per block in gemm tiles
#define ECAP 64  // edges stashed in LDS per node (recompute tail beyond)

// ---------------- CSR build ----------------

__global__ void k_hist(const int* __restrict__ dst, int* __restrict__ deg){
  int e = blockIdx.x*256+threadIdx.x;
  if (e < N_EDGES) atomicAdd(&deg[dst[e]], 1);
}

__global__ void k_block_sums(const int* __restrict__ deg, int* __restrict__ bsums){
  int i = blockIdx.x*256+threadIdx.x;
  int v = (i<N_NODES)? deg[i]:0;
  #pragma unroll
  for (int o=32;o>=1;o>>=1) v += __shfl_xor(v,o,64);
  __shared__ int ws[4];
  if ((threadIdx.x&63)==0) ws[threadIdx.x>>6]=v;
  __syncthreads();
  if (threadIdx.x==0) bsums[blockIdx.x]=ws[0]+ws[1]+ws[2]+ws[3];
}

__global__ void k_scan_bsums(int* bsums, int nb){
  if (threadIdx.x==0 && blockIdx.x==0){
    int a=0;
    for (int i=0;i<nb;i++){int t=bsums[i]; bsums[i]=a; a+=t;}
  }
}

__device__ inline int wave_incl_scan(int v){
  int lane = threadIdx.x & 63;
  #pragma unroll
  for (int o=1;o<64;o<<=1){
    int t = __shfl_up(v,o,64);
    if (lane>=o) v+=t;
  }
  return v;
}

__global__ void k_scan_chunks(const int* __restrict__ deg, const int* __restrict__ bsums,
                              int* __restrict__ offs, int* __restrict__ cursor){
  int i = blockIdx.x*256+threadIdx.x;
  int v = (i<N_NODES)? deg[i]:0;
  int incl = wave_incl_scan(v);
  __shared__ int ws[4];
  int wid=threadIdx.x>>6, lane=threadIdx.x&63;
  if (lane==63) ws[wid]=incl;
  __syncthreads();
  if (threadIdx.x==0){int a=0; for(int w=0;w<4;w++){int t=ws[w];ws[w]=a;a+=t;}}
  __syncthreads();
  int excl = incl - v + ws[wid] + bsums[blockIdx.x];
  if (i<N_NODES){ offs[i]=excl; cursor[i]=excl; }
  if (i==N_NODES-1) offs[N_NODES]=excl+v;
}

__global__ void k_scatter(const int* __restrict__ src, const int* __restrict__ dst,
                          int* __restrict__ cursor, int* __restrict__ csr_src,
                          int* __restrict__ csr_eid){
  int e = blockIdx.x*256+threadIdx.x;
  if (e<N_EDGES){
    int d = dst[e];
    int pos = atomicAdd(&cursor[d],1);
    csr_src[pos]=src[e];
    csr_eid[pos]=e;
  }
}

// ---------------- GEMM tile kernel (shared shape) ----------------
// 32-node M-tile in LDS; thread = 8 cols x 4 nodes; fused el/er

template<int K>
__global__ __launch_bounds__(256) void k_gemm_t(const float* __restrict__ x, const float* __restrict__ W,
   const float* __restrict__ al, const float* __restrict__ ar,
   float* __restrict__ feat, float* __restrict__ el, float* __restrict__ er){
  __shared__ float xs[K][TM+4];
  int tid=threadIdx.x;
  int nb = blockIdx.x*TM;
  if (K==HD){
    for (int i=0;i<TM;i++){
      int node = nb+i;
      xs[tid][i] = (node<N_NODES)? x[(size_t)node*K+tid] : 0.f;
    }
  } else {
    // K==32: thread t loads float4 of node nb+(t>>3), cols (t&7)*4..+3
    int i = tid>>3, k0=(tid&7)*4;
    int node = nb+i;
    float4 v = (node<N_NODES)? *(const float4*)&x[(size_t)node*K+k0] : make_float4(0,0,0,0);
    xs[k0+0][i]=v.x; xs[k0+1][i]=v.y; xs[k0+2][i]=v.z; xs[k0+3][i]=v.w;
  }
  __syncthreads();
  int c0 = tid&31;
  int nl0 = (tid>>5)*4;
  float acc[8][4];
  #pragma unroll
  for(int c=0;c<8;c++)
    #pragma unroll
    for(int nn=0;nn<4;nn++) acc[c][nn]=0.f;
  #pragma unroll 2
  for (int k=0;k<K;k++){
    float4 xv = *(const float4*)&xs[k][nl0];
    float w[8];
    #pragma unroll
    for(int c=0;c<8;c++) w[c]=W[(size_t)k*HD + c0 + 32*c];
    #pragma unroll
    for(int c=0;c<8;c++){
      acc[c][0]=fmaf(w[c],xv.x,acc[c][0]);
      acc[c][1]=fmaf(w[c],xv.y,acc[c][1]);
      acc[c][2]=fmaf(w[c],xv.z,acc[c][2]);
      acc[c][3]=fmaf(w[c],xv.w,acc[c][3]);
    }
  }
  #pragma unroll
  for (int nn=0;nn<4;nn++){
    int node = nb+nl0+nn;
    if (node<N_NODES){
      #pragma unroll
      for(int c=0;c<8;c++) feat[(size_t)node*HD + c0+32*c] = acc[c][nn];
    }
  }
  #pragma unroll
  for (int nn=0;nn<4;nn++){
    int node = nb+nl0+nn;
    #pragma unroll
    for (int c=0;c<8;c++){
      float pl = acc[c][nn]*al[c*32+c0];
      float pr = acc[c][nn]*ar[c*32+c0];
      #pragma unroll
      for(int o=16;o>=1;o>>=1){ pl+=__shfl_xor(pl,o,64); pr+=__shfl_xor(pr,o,64); }
      if (c0==0 && node<N_NODES){ el[node*H_+c]=pl; er[node*H_+c]=pr; }
    }
  }
}

// ---------------- edge softmax + aggregate: one WAVE per node ----------------
// lane = (head h = lane>>3, sub = lane&7) in phase A; dims 4*lane..+3 in phase B.

template<int LAYER>
__global__ __launch_bounds__(256) void k_agg(const int* __restrict__ offs, const int* __restrict__ csr_src,
   const int* __restrict__ csr_eid, const float* __restrict__ feat,
   const float* __restrict__ el, const float* __restrict__ er, const float* __restrict__ bias,
   float* __restrict__ out, float* __restrict__ alpha_out){
  __shared__ float s_sc[4][ECAP][H_];  // raw scores
  __shared__ int   s_sn[4][ECAP];      // src node ids
  __shared__ int   s_eid[4][ECAP];     // edge ids (layer 1 only)
  int w = threadIdx.x>>6, lane = threadIdx.x&63;
  int n = blockIdx.x*4 + w;            // N_NODES % 4 == 0
  int h = lane>>3, sub = lane&7;
  int off = offs[n], deg = offs[n+1]-off;
  float er_n = er[n*H_+h];

  // ---- phase A: scores -> LDS, online (m,s) ----
  float m=-1e30f, s=0.f;
  for (int i=sub; i<deg; i+=8){
    int p = off+i;
    int sn = csr_src[p];
    float sc = el[sn*H_+h]+er_n;
    sc = sc>0.f? sc : 0.2f*sc;
    if (i<ECAP){
      s_sc[w][i][h]=sc;
      if (h==0){
        s_sn[w][i]=sn;
        if (LAYER==1) s_eid[w][i]=csr_eid[p];
      }
    }
    float mn = fmaxf(m,sc);
    s = s*__expf(m-mn) + __expf(sc-mn);
    m = mn;
  }
  #pragma unroll
  for (int o=4;o>=1;o>>=1){
    float m2=__shfl_xor(m,o,64), s2=__shfl_xor(s,o,64);
    float mn=fmaxf(m,m2);
    s = s*__expf(m-mn) + s2*__expf(m2-mn);
    m = mn;
  }
  float inv_s = (s>0.f)? 1.f/s : 0.f;
  __syncthreads();

  // ---- phase B: alpha-weighted gather, 4x unrolled ----
  int d0 = 4*lane;
  float4 acc0 = make_float4(0,0,0,0), acc1 = make_float4(0,0,0,0);
  int dcap = deg<ECAP? deg:ECAP;
  int i=0;
  for (; i+4<=dcap; i+=4){
    int sn0=s_sn[w][i], sn1=s_sn[w][i+1], sn2=s_sn[w][i+2], sn3=s_sn[w][i+3];
    float a0=__expf(s_sc[w][i  ][h]-m)*inv_s;
    float a1=__expf(s_sc[w][i+1][h]-m)*inv_s;
    float a2=__expf(s_sc[w][i+2][h]-m)*inv_s;
    float a3=__expf(s_sc[w][i+3][h]-m)*inv_s;
    float4 f0=*(const float4*)&feat[(size_t)sn0*HD+d0];
    float4 f1=*(const float4*)&feat[(size_t)sn1*HD+d0];
    float4 f2=*(const float4*)&feat[(size_t)sn2*HD+d0];
    float4 f3=*(const float4*)&feat[(size_t)sn3*HD+d0];
    acc0.x=fmaf(a0,f0.x,acc0.x); acc0.y=fmaf(a0,f0.y,acc0.y); acc0.z=fmaf(a0,f0.z,acc0.z); acc0.w=fmaf(a0,f0.w,acc0.w);
    acc1.x=fmaf(a1,f1.x,acc1.x); acc1.y=fmaf(a1,f1.y,acc1.y); acc1.z=fmaf(a1,f1.z,acc1.z); acc1.w=fmaf(a1,f1.w,acc1.w);
    acc0.x=fmaf(a2,f2.x,acc0.x); acc0.y=fmaf(a2,f2.y,acc0.y); acc0.z=fmaf(a2,f2.z,acc0.z); acc0.w=fmaf(a2,f2.w,acc0.w);
    acc1.x=fmaf(a3,f3.x,acc1.x); acc1.y=fmaf(a3,f3.y,acc1.y); acc1.z=fmaf(a3,f3.z,acc1.z); acc1.w=fmaf(a3,f3.w,acc1.w);
    if (LAYER==1 && sub==0){
      alpha_out[(size_t)s_eid[w][i  ]*H_+h]=a0;
      alpha_out[(size_t)s_eid[w][i+1]*H_+h]=a1;
      alpha_out[(size_t)s_eid[w][i+2]*H_+h]=a2;
      alpha_out[(size_t)s_eid[w][i+3]*H_+h]=a3;
    }
  }
  for (; i<dcap; ++i){
    int sn = s_sn[w][i];
    float a=__expf(s_sc[w][i][h]-m)*inv_s;
    float4 fv=*(const float4*)&feat[(size_t)sn*HD+d0];
    acc0.x=fmaf(a,fv.x,acc0.x); acc0.y=fmaf(a,fv.y,acc0.y); acc0.z=fmaf(a,fv.z,acc0.z); acc0.w=fmaf(a,fv.w,acc0.w);
    if (LAYER==1 && sub==0) alpha_out[(size_t)s_eid[w][i]*H_+h]=a;
  }
  for (; i<deg; ++i){            // rare tail: deg > ECAP, recompute score
    int p = off+i;
    int sn = csr_src[p];
    float sc = el[sn*H_+h]+er_n;
    sc = sc>0.f? sc : 0.2f*sc;
    float a=__expf(sc-m)*inv_s;
    float4 fv=*(const float4*)&feat[(size_t)sn*HD+d0];
    acc0.x=fmaf(a,fv.x,acc0.x); acc0.y=fmaf(a,fv.y,acc0.y); acc0.z=fmaf(a,fv.z,acc0.z); acc0.w=fmaf(a,fv.w,acc0.w);
    if (LAYER==1 && sub==0) alpha_out[(size_t)csr_eid[p]*H_+h]=a;
  }

  float4 v;
  v.x = acc0.x+acc1.x + bias[d0+0];
  v.y = acc0.y+acc1.y + bias[d0+1];
  v.z = acc0.z+acc1.z + bias[d0+2];
  v.w = acc0.w+acc1.w + bias[d0+3];
  if (LAYER==0){
    v.x=fmaxf(v.x,0.f); v.y=fmaxf(v.y,0.f); v.z=fmaxf(v.z,0.f); v.w=fmaxf(v.w,0.f);
    *(float4*)&out[(size_t)n*HD+d0] = v;
  } else {
    // mean over heads: sum across lanes with same (lane&7) -> xor 8,16,32
    #pragma unroll
    for (int o=8;o<64;o<<=1){
      v.x+=__shfl_xor(v.x,o,64);
      v.y+=__shfl_xor(v.y,o,64);
      v.z+=__shfl_xor(v.z,o,64);
      v.w+=__shfl_xor(v.w,o,64);
    }
    if (h==0){
      v.x*=0.125f; v.y*=0.125f; v.z*=0.125f; v.w*=0.125f;
      *(float4*)&out[(size_t)n*D_+4*sub] = v;
    }
  }
}

// ---------------- launcher ----------------

extern "C" void kernel_launch(void* const* d_in, const int* in_sizes, int n_in,
                              void* d_out, int out_size, void* d_ws, size_t ws_size,
                              hipStream_t stream){
  const float* h   = (const float*)d_in[0];
  const int*   src = (const int*)d_in[1];
  const int*   dst = (const int*)d_in[2];
  const float* W0  = (const float*)d_in[3];
  const float* al0 = (const float*)d_in[4];
  const float* ar0 = (const float*)d_in[5];
  const float* b0  = (const float*)d_in[6];
  const float* W1  = (const float*)d_in[7];
  const float* al1 = (const float*)d_in[8];
  const float* ar1 = (const float*)d_in[9];
  const float* b1  = (const float*)d_in[10];
  float* out_final = (float*)d_out;
  float* alpha_out = (float*)d_out + (size_t)N_NODES*D_;

  char* wsp = (char*)d_ws;
  auto alloc=[&](size_t bytes)->char*{ char* p=wsp; wsp += (bytes+255)&~size_t(255); return p; };
  int*   deg     = (int*)alloc((size_t)N_NODES*4);
  int*   offs    = (int*)alloc((size_t)(N_NODES+1)*4);
  int*   cursor  = (int*)alloc((size_t)N_NODES*4);
  int*   bsums   = (int*)alloc(1024);
  int*   csr_src = (int*)alloc((size_t)N_EDGES*4);
  int*   csr_eid = (int*)alloc((size_t)N_EDGES*4);
  float* feat    = (float*)alloc((size_t)N_NODES*HD*4);
  float* h1      = (float*)alloc((size_t)N_NODES*HD*4);
  float* el      = (float*)alloc((size_t)N_NODES*H_*4);
  float* er      = (float*)alloc((size_t)N_NODES*H_*4);

  hipMemsetAsync(deg, 0, (size_t)N_NODES*4, stream);
  int eb = (N_EDGES+255)/256;
  int nbchunks = (N_NODES+255)/256;
  k_hist       <<<eb,      256,0,stream>>>(dst, deg);
  k_block_sums <<<nbchunks,256,0,stream>>>(deg, bsums);
  k_scan_bsums <<<1,       64, 0,stream>>>(bsums, nbchunks);
  k_scan_chunks<<<nbchunks,256,0,stream>>>(deg, bsums, offs, cursor);
  k_scatter    <<<eb,      256,0,stream>>>(src, dst, cursor, csr_src, csr_eid);

  int gb = (N_NODES+TM-1)/TM;
  k_gemm_t<IN_DIM><<<gb,256,0,stream>>>(h, W0, al0, ar0, feat, el, er);
  k_agg<0><<<N_NODES/4,256,0,stream>>>(offs, csr_src, csr_eid, feat, el, er, b0, h1, nullptr);
  k_gemm_t<HD><<<gb,256,0,stream>>>(h1, W1, al1, ar1, feat, el, er);
  k_agg<1><<<N_NODES/4,256,0,stream>>>(offs, csr_src, csr_eid, feat, el, er, b1, out_final, alpha_out);
}

// Round 4
// 528.454 us; speedup vs baseline: 1.5899x; 1.0580x over previous
//
#include <hip/hip_runtime.h>

#define N_NODES 50000
#define N_EDGES 800000
#define IN_DIM 32
#define HD 256   // H*D
#define H_ 8
#define D_ 32
#define TM 64    // nodes per block in k_gemm1
#define ECAP 64  // edges stashed in LDS per node (recompute tail beyond)

// ---------------- CSR build ----------------

__global__ void k_hist(const int* __restrict__ dst, int* __restrict__ deg){
  int e = blockIdx.x*256+threadIdx.x;
  if (e < N_EDGES) atomicAdd(&deg[dst[e]], 1);
}

__global__ void k_block_sums(const int* __restrict__ deg, int* __restrict__ bsums){
  int i = blockIdx.x*256+threadIdx.x;
  int v = (i<N_NODES)? deg[i]:0;
  #pragma unroll
  for (int o=32;o>=1;o>>=1) v += __shfl_xor(v,o,64);
  __shared__ int ws[4];
  if ((threadIdx.x&63)==0) ws[threadIdx.x>>6]=v;
  __syncthreads();
  if (threadIdx.x==0) bsums[blockIdx.x]=ws[0]+ws[1]+ws[2]+ws[3];
}

__global__ void k_scan_bsums(int* bsums, int nb){
  if (threadIdx.x==0 && blockIdx.x==0){
    int a=0;
    for (int i=0;i<nb;i++){int t=bsums[i]; bsums[i]=a; a+=t;}
  }
}

__device__ inline int wave_incl_scan(int v){
  int lane = threadIdx.x & 63;
  #pragma unroll
  for (int o=1;o<64;o<<=1){
    int t = __shfl_up(v,o,64);
    if (lane>=o) v+=t;
  }
  return v;
}

__global__ void k_scan_chunks(const int* __restrict__ deg, const int* __restrict__ bsums,
                              int* __restrict__ offs, int* __restrict__ cursor){
  int i = blockIdx.x*256+threadIdx.x;
  int v = (i<N_NODES)? deg[i]:0;
  int incl = wave_incl_scan(v);
  __shared__ int ws[4];
  int wid=threadIdx.x>>6, lane=threadIdx.x&63;
  if (lane==63) ws[wid]=incl;
  __syncthreads();
  if (threadIdx.x==0){int a=0; for(int w=0;w<4;w++){int t=ws[w];ws[w]=a;a+=t;}}
  __syncthreads();
  int excl = incl - v + ws[wid] + bsums[blockIdx.x];
  if (i<N_NODES){ offs[i]=excl; cursor[i]=excl; }
  if (i==N_NODES-1) offs[N_NODES]=excl+v;
}

__global__ void k_scatter(const int* __restrict__ src, const int* __restrict__ dst,
                          int* __restrict__ cursor, int* __restrict__ csr_src,
                          int* __restrict__ csr_eid){
  int e = blockIdx.x*256+threadIdx.x;
  if (e<N_EDGES){
    int d = dst[e];
    int pos = atomicAdd(&cursor[d],1);
    csr_src[pos]=src[e];
    csr_eid[pos]=e;
  }
}

// ---------------- Wa precompute: Wa[k][h]=sum_d W[k][h*32+d]*al[h][d] (h<8), ar for h>=8 ----------------

template<int K>
__global__ void k_prep(const float* __restrict__ W, const float* __restrict__ al,
                       const float* __restrict__ ar, float* __restrict__ Wa){
  int t = blockIdx.x*256 + threadIdx.x;
  int k = t>>3, hh = t&7;
  if (k < K){
    float sl=0.f, sr=0.f;
    #pragma unroll
    for (int d=0; d<32; d++){
      float w = W[(size_t)k*HD + hh*32 + d];
      sl = fmaf(w, al[hh*32+d], sl);
      sr = fmaf(w, ar[hh*32+d], sr);
    }
    Wa[k*16 + hh]     = sl;
    Wa[k*16 + 8 + hh] = sr;
  }
}

// ---------------- el/er: elr[n*16+j] = sum_k x[n,k]*Wa[k,j] ----------------
// block = 16 nodes x 16 j-lanes

template<int K>
__global__ __launch_bounds__(256) void k_el(const float* __restrict__ x, const float* __restrict__ Wa,
                                            float* __restrict__ elr){
  __shared__ float sWa[K*16];
  __shared__ float sx[16][K+1];
  int tid = threadIdx.x;
  int nb = blockIdx.x*16;
  for (int i = tid; i < K*16; i += 256) sWa[i] = Wa[i];
  for (int i = tid; i < 16*K; i += 256){
    int r = i / K, c = i % K;
    sx[r][c] = x[(size_t)(nb+r)*K + c];
  }
  __syncthreads();
  int node = tid>>4, j = tid&15;
  float s = 0.f;
  #pragma unroll 8
  for (int k=0;k<K;k++) s = fmaf(sx[node][k], sWa[k*16+j], s);
  elr[(size_t)(nb+node)*16 + j] = s;
}

// ---------------- layer-0 aggregate of raw x (per head): hagg[n][h][d] ----------------
// one wave per node; phase A: (h=lane>>3, sub=lane&7); phase B: (hw=lane>>5 edge parity, d=lane&31)

__global__ __launch_bounds__(256) void k_agg0(const int* __restrict__ offs, const int* __restrict__ csr_src,
    const float* __restrict__ x, const float* __restrict__ elr, float* __restrict__ hagg){
  __shared__ float s_al[4][ECAP][H_];
  __shared__ int   s_sn[4][ECAP];
  __shared__ float s_m[4][H_], s_is[4][H_];
  int w = threadIdx.x>>6, lane = threadIdx.x&63;
  int n = blockIdx.x*4 + w;
  int h = lane>>3, sub = lane&7;
  int off = offs[n], deg = offs[n+1]-off;
  float er_n = elr[n*16 + 8 + h];

  float m=-1e30f, s=0.f;
  for (int i=sub; i<deg; i+=8){
    int sn = csr_src[off+i];
    float sc = elr[sn*16+h] + er_n;
    sc = sc>0.f? sc : 0.2f*sc;
    if (i<ECAP){ s_al[w][i][h] = sc; if (h==0) s_sn[w][i] = sn; }
    float mn = fmaxf(m,sc);
    s = s*__expf(m-mn) + __expf(sc-mn);
    m = mn;
  }
  #pragma unroll
  for (int o=4;o>=1;o>>=1){
    float m2=__shfl_xor(m,o,64), s2=__shfl_xor(s,o,64);
    float mn=fmaxf(m,m2);
    s = s*__expf(m-mn)+s2*__expf(m2-mn); m=mn;
  }
  float inv_s = (s>0.f)?1.f/s:0.f;
  if (sub==0){ s_m[w][h]=m; s_is[w][h]=inv_s; }
  int dcap = deg<ECAP? deg:ECAP;
  for (int i=sub; i<dcap; i+=8)           // scores -> alphas (same lane rewrites its own entries)
    s_al[w][i][h] = __expf(s_al[w][i][h]-m)*inv_s;
  __syncthreads();

  // phase B: 2 edges in flight (half-wave each), lane covers dim d for all 8 heads
  int hw = lane>>5, d = lane&31;
  float acc[H_] = {0,0,0,0,0,0,0,0};
  int i = hw;
  for (; i<dcap; i+=2){
    int sn = s_sn[w][i];
    float xv = x[(size_t)sn*IN_DIM + d];
    float4 a0 = *(const float4*)&s_al[w][i][0];
    float4 a1 = *(const float4*)&s_al[w][i][4];
    acc[0]=fmaf(a0.x,xv,acc[0]); acc[1]=fmaf(a0.y,xv,acc[1]);
    acc[2]=fmaf(a0.z,xv,acc[2]); acc[3]=fmaf(a0.w,xv,acc[3]);
    acc[4]=fmaf(a1.x,xv,acc[4]); acc[5]=fmaf(a1.y,xv,acc[5]);
    acc[6]=fmaf(a1.z,xv,acc[6]); acc[7]=fmaf(a1.w,xv,acc[7]);
  }
  for (; i<deg; i+=2){                    // rare tail: recompute
    int sn = csr_src[off+i];
    float xv = x[(size_t)sn*IN_DIM + d];
    #pragma unroll
    for (int hh=0;hh<H_;hh++){
      float sc = elr[sn*16+hh] + elr[n*16+8+hh];
      sc = sc>0.f? sc : 0.2f*sc;
      float a = __expf(sc - s_m[w][hh]) * s_is[w][hh];
      acc[hh]=fmaf(a,xv,acc[hh]);
    }
  }
  #pragma unroll
  for (int hh=0;hh<H_;hh++) acc[hh] += __shfl_xor(acc[hh],32,64);
  if (hw==0){
    #pragma unroll
    for (int hh=0;hh<H_;hh++) hagg[((size_t)n*H_+hh)*D_ + d] = acc[hh];
  }
}

// ---------------- h1 = relu(hagg @ blockdiag(W0) + b0), one wave per node ----------------
// lane: 4 consecutive cols col0=4*lane (same head h=lane>>3); hagg row staged transposed in LDS

__global__ __launch_bounds__(256) void k_gemm_h1(const float* __restrict__ hagg, const float* __restrict__ W0,
    const float* __restrict__ b0, float* __restrict__ h1){
  __shared__ float s_hg[4][HD];   // [k*8+h] transposed layout
  int w = threadIdx.x>>6, lane = threadIdx.x&63;
  int n = blockIdx.x*4 + w;
  {
    float4 v = *(const float4*)&hagg[(size_t)n*HD + lane*4];
    int h = lane>>3, k0 = (lane*4)&31;
    s_hg[w][(k0+0)*8+h]=v.x; s_hg[w][(k0+1)*8+h]=v.y;
    s_hg[w][(k0+2)*8+h]=v.z; s_hg[w][(k0+3)*8+h]=v.w;
  }
  __syncthreads();
  int col0 = lane*4;
  int h = lane>>3;
  float4 acc = make_float4(0,0,0,0);
  #pragma unroll 8
  for (int k=0;k<IN_DIM;k++){
    float hv = s_hg[w][k*8+h];
    float4 wv = *(const float4*)&W0[(size_t)k*HD + col0];
    acc.x=fmaf(hv,wv.x,acc.x); acc.y=fmaf(hv,wv.y,acc.y);
    acc.z=fmaf(hv,wv.z,acc.z); acc.w=fmaf(hv,wv.w,acc.w);
  }
  float4 bv = *(const float4*)&b0[col0];
  acc.x=fmaxf(acc.x+bv.x,0.f); acc.y=fmaxf(acc.y+bv.y,0.f);
  acc.z=fmaxf(acc.z+bv.z,0.f); acc.w=fmaxf(acc.w+bv.w,0.f);
  *(float4*)&h1[(size_t)n*HD + col0] = acc;
}

// ---------------- feat1 = h1 @ W1 (64-node tile, 8 nodes/thread) ----------------

__global__ __launch_bounds__(256) void k_gemm1(const float* __restrict__ x, const float* __restrict__ W,
                                               float* __restrict__ feat){
  __shared__ float xs[HD][TM+4];
  int tid=threadIdx.x;
  int nb = blockIdx.x*TM;
  for (int c=0;c<TM;c++){
    int node = nb+c;
    xs[tid][c] = (node<N_NODES)? x[(size_t)node*HD+tid] : 0.f;
  }
  __syncthreads();
  int c0 = tid&31;
  int nl0 = (tid>>5)*8;
  float acc[8][8];
  #pragma unroll
  for(int c=0;c<8;c++)
    #pragma unroll
    for(int nn=0;nn<8;nn++) acc[c][nn]=0.f;
  #pragma unroll 4
  for (int k=0;k<HD;k++){
    float4 xa = *(const float4*)&xs[k][nl0];
    float4 xb = *(const float4*)&xs[k][nl0+4];
    float wv[8];
    #pragma unroll
    for(int c=0;c<8;c++) wv[c]=W[(size_t)k*HD + c0 + 32*c];
    #pragma unroll
    for(int c=0;c<8;c++){
      acc[c][0]=fmaf(wv[c],xa.x,acc[c][0]);
      acc[c][1]=fmaf(wv[c],xa.y,acc[c][1]);
      acc[c][2]=fmaf(wv[c],xa.z,acc[c][2]);
      acc[c][3]=fmaf(wv[c],xa.w,acc[c][3]);
      acc[c][4]=fmaf(wv[c],xb.x,acc[c][4]);
      acc[c][5]=fmaf(wv[c],xb.y,acc[c][5]);
      acc[c][6]=fmaf(wv[c],xb.z,acc[c][6]);
      acc[c][7]=fmaf(wv[c],xb.w,acc[c][7]);
    }
  }
  #pragma unroll
  for (int nn=0;nn<8;nn++){
    int node = nb+nl0+nn;
    if (node<N_NODES){
      #pragma unroll
      for(int c=0;c<8;c++) feat[(size_t)node*HD + c0+32*c] = acc[c][nn];
    }
  }
}

// ---------------- layer-1 edge softmax + aggregate + head-mean ----------------
// one wave per node; phase A (h=lane>>3,sub=lane&7); phase B dims d0=4*lane, head lane>>3

__global__ __launch_bounds__(256) void k_agg1(const int* __restrict__ offs, const int* __restrict__ csr_src,
   const int* __restrict__ csr_eid, const float* __restrict__ feat, const float* __restrict__ elr,
   const float* __restrict__ bias, float* __restrict__ out, float* __restrict__ alpha_out){
  __shared__ float s_al[4][ECAP][H_];
  __shared__ int   s_sn[4][ECAP];
  __shared__ int   s_eid[4][ECAP];
  int w = threadIdx.x>>6, lane = threadIdx.x&63;
  int n = blockIdx.x*4 + w;
  int h = lane>>3, sub = lane&7;
  int off = offs[n], deg = offs[n+1]-off;
  float er_n = elr[n*16 + 8 + h];

  float m=-1e30f, s=0.f;
  for (int i=sub; i<deg; i+=8){
    int p = off+i;
    int sn = csr_src[p];
    float sc = elr[sn*16+h] + er_n;
    sc = sc>0.f? sc : 0.2f*sc;
    if (i<ECAP){
      s_al[w][i][h]=sc;
      if (h==0){ s_sn[w][i]=sn; s_eid[w][i]=csr_eid[p]; }
    }
    float mn = fmaxf(m,sc);
    s = s*__expf(m-mn) + __expf(sc-mn);
    m = mn;
  }
  #pragma unroll
  for (int o=4;o>=1;o>>=1){
    float m2=__shfl_xor(m,o,64), s2=__shfl_xor(s,o,64);
    float mn=fmaxf(m,m2);
    s = s*__expf(m-mn) + s2*__expf(m2-mn);
    m = mn;
  }
  float inv_s = (s>0.f)? 1.f/s : 0.f;
  int dcap = deg<ECAP? deg:ECAP;
  __syncthreads();   // s_eid ready before conversion pass writes alpha
  for (int i=sub; i<dcap; i+=8){
    float a = __expf(s_al[w][i][h]-m)*inv_s;
    s_al[w][i][h] = a;
    alpha_out[(size_t)s_eid[w][i]*H_ + h] = a;
  }
  __syncthreads();

  // phase B
  int d0 = 4*lane;
  float4 acc0 = make_float4(0,0,0,0), acc1 = make_float4(0,0,0,0);
  int i=0;
  for (; i+4<=dcap; i+=4){
    int sn0=s_sn[w][i], sn1=s_sn[w][i+1], sn2=s_sn[w][i+2], sn3=s_sn[w][i+3];
    float a0=s_al[w][i  ][h];
    float a1=s_al[w][i+1][h];
    float a2=s_al[w][i+2][h];
    float a3=s_al[w][i+3][h];
    float4 f0=*(const float4*)&feat[(size_t)sn0*HD+d0];
    float4 f1=*(const float4*)&feat[(size_t)sn1*HD+d0];
    float4 f2=*(const float4*)&feat[(size_t)sn2*HD+d0];
    float4 f3=*(const float4*)&feat[(size_t)sn3*HD+d0];
    acc0.x=fmaf(a0,f0.x,acc0.x); acc0.y=fmaf(a0,f0.y,acc0.y); acc0.z=fmaf(a0,f0.z,acc0.z); acc0.w=fmaf(a0,f0.w,acc0.w);
    acc1.x=fmaf(a1,f1.x,acc1.x); acc1.y=fmaf(a1,f1.y,acc1.y); acc1.z=fmaf(a1,f1.z,acc1.z); acc1.w=fmaf(a1,f1.w,acc1.w);
    acc0.x=fmaf(a2,f2.x,acc0.x); acc0.y=fmaf(a2,f2.y,acc0.y); acc0.z=fmaf(a2,f2.z,acc0.z); acc0.w=fmaf(a2,f2.w,acc0.w);
    acc1.x=fmaf(a3,f3.x,acc1.x); acc1.y=fmaf(a3,f3.y,acc1.y); acc1.z=fmaf(a3,f3.z,acc1.z); acc1.w=fmaf(a3,f3.w,acc1.w);
  }
  for (; i<dcap; ++i){
    int sn = s_sn[w][i];
    float a=s_al[w][i][h];
    float4 fv=*(const float4*)&feat[(size_t)sn*HD+d0];
    acc0.x=fmaf(a,fv.x,acc0.x); acc0.y=fmaf(a,fv.y,acc0.y); acc0.z=fmaf(a,fv.z,acc0.z); acc0.w=fmaf(a,fv.w,acc0.w);
  }
  for (; i<deg; ++i){            // rare tail: deg > ECAP
    int p = off+i;
    int sn = csr_src[p];
    float sc = elr[sn*16+h] + er_n;
    sc = sc>0.f? sc : 0.2f*sc;
    float a=__expf(sc-m)*inv_s;
    float4 fv=*(const float4*)&feat[(size_t)sn*HD+d0];
    acc0.x=fmaf(a,fv.x,acc0.x); acc0.y=fmaf(a,fv.y,acc0.y); acc0.z=fmaf(a,fv.z,acc0.z); acc0.w=fmaf(a,fv.w,acc0.w);
    if (sub==0) alpha_out[(size_t)csr_eid[p]*H_+h]=a;
  }

  float4 v;
  v.x = acc0.x+acc1.x + bias[d0+0];
  v.y = acc0.y+acc1.y + bias[d0+1];
  v.z = acc0.z+acc1.z + bias[d0+2];
  v.w = acc0.w+acc1.w + bias[d0+3];
  #pragma unroll
  for (int o=8;o<64;o<<=1){
    v.x+=__shfl_xor(v.x,o,64);
    v.y+=__shfl_xor(v.y,o,64);
    v.z+=__shfl_xor(v.z,o,64);
    v.w+=__shfl_xor(v.w,o,64);
  }
  if (h==0){
    v.x*=0.125f; v.y*=0.125f; v.z*=0.125f; v.w*=0.125f;
    *(float4*)&out[(size_t)n*D_+4*sub] = v;
  }
}

// ---------------- launcher ----------------

extern "C" void kernel_launch(void* const* d_in, const int* in_sizes, int n_in,
                              void* d_out, int out_size, void* d_ws, size_t ws_size,
                              hipStream_t stream){
  const float* h   = (const float*)d_in[0];
  const int*   src = (const int*)d_in[1];
  const int*   dst = (const int*)d_in[2];
  const float* W0  = (const float*)d_in[3];
  const float* al0 = (const float*)d_in[4];
  const float* ar0 = (const float*)d_in[5];
  const float* b0  = (const float*)d_in[6];
  const float* W1  = (const float*)d_in[7];
  const float* al1 = (const float*)d_in[8];
  const float* ar1 = (const float*)d_in[9];
  const float* b1  = (const float*)d_in[10];
  float* out_final = (float*)d_out;
  float* alpha_out = (float*)d_out + (size_t)N_NODES*D_;

  char* wsp = (char*)d_ws;
  auto alloc=[&](size_t bytes)->char*{ char* p=wsp; wsp += (bytes+255)&~size_t(255); return p; };
  int*   deg     = (int*)alloc((size_t)N_NODES*4);
  int*   offs    = (int*)alloc((size_t)(N_NODES+1)*4);
  int*   cursor  = (int*)alloc((size_t)N_NODES*4);
  int*   bsums   = (int*)alloc(1024);
  int*   csr_src = (int*)alloc((size_t)N_EDGES*4);
  int*   csr_eid = (int*)alloc((size_t)N_EDGES*4);
  float* bufA    = (float*)alloc((size_t)N_NODES*HD*4);  // hagg, later feat1
  float* h1      = (float*)alloc((size_t)N_NODES*HD*4);
  float* elr0    = (float*)alloc((size_t)N_NODES*16*4);
  float* elr1    = (float*)alloc((size_t)N_NODES*16*4);
  float* Wa0     = (float*)alloc((size_t)IN_DIM*16*4);
  float* Wa1     = (float*)alloc((size_t)HD*16*4);
  float* hagg    = bufA;
  float* feat1   = bufA;   // reuse: hagg dead after k_gemm_h1

  hipMemsetAsync(deg, 0, (size_t)N_NODES*4, stream);
  int eb = (N_EDGES+255)/256;
  int nbchunks = (N_NODES+255)/256;
  k_hist       <<<eb,      256,0,stream>>>(dst, deg);
  k_block_sums <<<nbchunks,256,0,stream>>>(deg, bsums);
  k_scan_bsums <<<1,       64, 0,stream>>>(bsums, nbchunks);
  k_scan_chunks<<<nbchunks,256,0,stream>>>(deg, bsums, offs, cursor);
  k_scatter    <<<eb,      256,0,stream>>>(src, dst, cursor, csr_src, csr_eid);

  k_prep<IN_DIM><<<1,256,0,stream>>>(W0, al0, ar0, Wa0);
  k_prep<HD>    <<<8,256,0,stream>>>(W1, al1, ar1, Wa1);

  k_el<IN_DIM><<<N_NODES/16,256,0,stream>>>(h, Wa0, elr0);
  k_agg0      <<<N_NODES/4, 256,0,stream>>>(offs, csr_src, h, elr0, hagg);
  k_gemm_h1   <<<N_NODES/4, 256,0,stream>>>(hagg, W0, b0, h1);
  k_el<HD>    <<<N_NODES/16,256,0,stream>>>(h1, Wa1, elr1);
  k_gemm1     <<<(N_NODES+TM-1)/TM,256,0,stream>>>(h1, W1, feat1);
  k_agg1      <<<N_NODES/4, 256,0,stream>>>(offs, csr_src, csr_eid, feat1, elr1, b1, out_final, alpha_out);
}

// Round 5
// 387.346 us; speedup vs baseline: 2.1691x; 1.3643x over previous
//
#include <hip/hip_runtime.h>

#define N_NODES 50000
#define N_EDGES 800000
#define IN_DIM 32
#define HD 256   // H*D
#define H_ 8
#define D_ 32
#define ECAP 64  // edges stashed in LDS per node (recompute tail beyond)

typedef __attribute__((ext_vector_type(8))) short bf16x8;
typedef __attribute__((ext_vector_type(4))) float f32x4;

__device__ inline unsigned short f2b(float f){
  union{float f;unsigned int u;}v; v.f=f;
  unsigned int r=(v.u + 0x7FFFu + ((v.u>>16)&1u))>>16;
  return (unsigned short)r;
}
__device__ inline float b2f(unsigned short u){
  union{float f;unsigned int u32;}v; v.u32=((unsigned int)u)<<16; return v.f;
}

// ---------------- CSR build ----------------

__global__ void k_hist(const int* __restrict__ dst, int* __restrict__ deg){
  int e = blockIdx.x*256+threadIdx.x;
  if (e < N_EDGES) atomicAdd(&deg[dst[e]], 1);
}

__global__ void k_block_sums(const int* __restrict__ deg, int* __restrict__ bsums){
  int i = blockIdx.x*256+threadIdx.x;
  int v = (i<N_NODES)? deg[i]:0;
  #pragma unroll
  for (int o=32;o>=1;o>>=1) v += __shfl_xor(v,o,64);
  __shared__ int ws[4];
  if ((threadIdx.x&63)==0) ws[threadIdx.x>>6]=v;
  __syncthreads();
  if (threadIdx.x==0) bsums[blockIdx.x]=ws[0]+ws[1]+ws[2]+ws[3];
}

__global__ void k_scan_bsums(int* bsums, int nb){
  if (threadIdx.x==0 && blockIdx.x==0){
    int a=0;
    for (int i=0;i<nb;i++){int t=bsums[i]; bsums[i]=a; a+=t;}
  }
}

__device__ inline int wave_incl_scan(int v){
  int lane = threadIdx.x & 63;
  #pragma unroll
  for (int o=1;o<64;o<<=1){
    int t = __shfl_up(v,o,64);
    if (lane>=o) v+=t;
  }
  return v;
}

__global__ void k_scan_chunks(const int* __restrict__ deg, const int* __restrict__ bsums,
                              int* __restrict__ offs, int* __restrict__ cursor){
  int i = blockIdx.x*256+threadIdx.x;
  int v = (i<N_NODES)? deg[i]:0;
  int incl = wave_incl_scan(v);
  __shared__ int ws[4];
  int wid=threadIdx.x>>6, lane=threadIdx.x&63;
  if (lane==63) ws[wid]=incl;
  __syncthreads();
  if (threadIdx.x==0){int a=0; for(int w=0;w<4;w++){int t=ws[w];ws[w]=a;a+=t;}}
  __syncthreads();
  int excl = incl - v + ws[wid] + bsums[blockIdx.x];
  if (i<N_NODES){ offs[i]=excl; cursor[i]=excl; }
  if (i==N_NODES-1) offs[N_NODES]=excl+v;
}

__global__ void k_scatter(const int* __restrict__ src, const int* __restrict__ dst,
                          int* __restrict__ cursor, int* __restrict__ csr_src,
                          int* __restrict__ csr_eid){
  int e = blockIdx.x*256+threadIdx.x;
  if (e<N_EDGES){
    int d = dst[e];
    int pos = atomicAdd(&cursor[d],1);
    csr_src[pos]=src[e];
    csr_eid[pos]=e;
  }
}

// ---------------- Wa precompute: Wa[k][h]=sum_d W[k][h*32+d]*al[h][d] (h<8), ar for h>=8 ----------------

template<int K>
__global__ void k_prep(const float* __restrict__ W, const float* __restrict__ al,
                       const float* __restrict__ ar, float* __restrict__ Wa){
  int t = blockIdx.x*256 + threadIdx.x;
  int k = t>>3, hh = t&7;
  if (k < K){
    float sl=0.f, sr=0.f;
    #pragma unroll
    for (int d=0; d<32; d++){
      float w = W[(size_t)k*HD + hh*32 + d];
      sl = fmaf(w, al[hh*32+d], sl);
      sr = fmaf(w, ar[hh*32+d], sr);
    }
    Wa[k*16 + hh]     = sl;
    Wa[k*16 + 8 + hh] = sr;
  }
}

// ---------------- W1 fragment pack: Wp[((ks*16+nt)*64+lane)*8+j] = bf16(W1[ks*32+8*(lane>>4)+j][nt*16+(lane&15)]) ----------------

__global__ void k_pack_w1(const float* __restrict__ W, unsigned short* __restrict__ Wp){
  int t = blockIdx.x*256+threadIdx.x;   // 65536 total
  int ks=(t>>13)&7, nt=(t>>9)&15, lane=(t>>3)&63, j=t&7;
  int k = ks*32 + (lane>>4)*8 + j;
  int col = nt*16 + (lane&15);
  Wp[t] = f2b(W[(size_t)k*HD+col]);
}

// ---------------- el/er (layer 0, f32 input K=32): elr[n*16+j] = sum_k x[n,k]*Wa[k,j] ----------------

template<int K>
__global__ __launch_bounds__(256) void k_el(const float* __restrict__ x, const float* __restrict__ Wa,
                                            float* __restrict__ elr){
  __shared__ float sWa[K*16];
  __shared__ float sx[16][K+1];
  int tid = threadIdx.x;
  int nb = blockIdx.x*16;
  for (int i = tid; i < K*16; i += 256) sWa[i] = Wa[i];
  for (int i = tid; i < 16*K; i += 256){
    int r = i / K, c = i % K;
    sx[r][c] = x[(size_t)(nb+r)*K + c];
  }
  __syncthreads();
  int node = tid>>4, j = tid&15;
  float s = 0.f;
  #pragma unroll 8
  for (int k=0;k<K;k++) s = fmaf(sx[node][k], sWa[k*16+j], s);
  elr[(size_t)(nb+node)*16 + j] = s;
}

// ---------------- el/er (layer 1, bf16 input K=256) ----------------

__global__ __launch_bounds__(256) void k_el_bf16(const unsigned short* __restrict__ x,
    const float* __restrict__ Wa, float* __restrict__ elr){
  __shared__ float sWa[HD*16];
  __shared__ float sx[16][HD+1];
  int tid = threadIdx.x;
  int nb = blockIdx.x*16;
  for (int i = tid; i < HD*16; i += 256) sWa[i] = Wa[i];
  for (int i = tid; i < 16*HD; i += 256){
    int r = i>>8, c = i&255;
    sx[r][c] = b2f(x[(size_t)(nb+r)*HD + c]);
  }
  __syncthreads();
  int node = tid>>4, j = tid&15;
  float s = 0.f;
  #pragma unroll 8
  for (int k=0;k<HD;k++) s = fmaf(sx[node][k], sWa[k*16+j], s);
  elr[(size_t)(nb+node)*16 + j] = s;
}

// ---------------- layer-0 aggregate of raw x (per head): hagg[n][h][d] ----------------

__global__ __launch_bounds__(256) void k_agg0(const int* __restrict__ offs, const int* __restrict__ csr_src,
    const float* __restrict__ x, const float* __restrict__ elr, float* __restrict__ hagg){
  __shared__ float s_al[4][ECAP][H_];
  __shared__ int   s_sn[4][ECAP];
  __shared__ float s_m[4][H_], s_is[4][H_];
  int w = threadIdx.x>>6, lane = threadIdx.x&63;
  int n = blockIdx.x*4 + w;
  int h = lane>>3, sub = lane&7;
  int off = offs[n], deg = offs[n+1]-off;
  float er_n = elr[n*16 + 8 + h];

  float m=-1e30f, s=0.f;
  for (int i=sub; i<deg; i+=8){
    int sn = csr_src[off+i];
    float sc = elr[sn*16+h] + er_n;
    sc = sc>0.f? sc : 0.2f*sc;
    if (i<ECAP){ s_al[w][i][h] = sc; if (h==0) s_sn[w][i] = sn; }
    float mn = fmaxf(m,sc);
    s = s*__expf(m-mn) + __expf(sc-mn);
    m = mn;
  }
  #pragma unroll
  for (int o=4;o>=1;o>>=1){
    float m2=__shfl_xor(m,o,64), s2=__shfl_xor(s,o,64);
    float mn=fmaxf(m,m2);
    s = s*__expf(m-mn)+s2*__expf(m2-mn); m=mn;
  }
  float inv_s = (s>0.f)?1.f/s:0.f;
  if (sub==0){ s_m[w][h]=m; s_is[w][h]=inv_s; }
  int dcap = deg<ECAP? deg:ECAP;
  for (int i=sub; i<dcap; i+=8)
    s_al[w][i][h] = __expf(s_al[w][i][h]-m)*inv_s;
  __syncthreads();

  int hw = lane>>5, d = lane&31;
  float acc[H_] = {0,0,0,0,0,0,0,0};
  int i = hw;
  for (; i<dcap; i+=2){
    int sn = s_sn[w][i];
    float xv = x[(size_t)sn*IN_DIM + d];
    float4 a0 = *(const float4*)&s_al[w][i][0];
    float4 a1 = *(const float4*)&s_al[w][i][4];
    acc[0]=fmaf(a0.x,xv,acc[0]); acc[1]=fmaf(a0.y,xv,acc[1]);
    acc[2]=fmaf(a0.z,xv,acc[2]); acc[3]=fmaf(a0.w,xv,acc[3]);
    acc[4]=fmaf(a1.x,xv,acc[4]); acc[5]=fmaf(a1.y,xv,acc[5]);
    acc[6]=fmaf(a1.z,xv,acc[6]); acc[7]=fmaf(a1.w,xv,acc[7]);
  }
  for (; i<deg; i+=2){
    int sn = csr_src[off+i];
    float xv = x[(size_t)sn*IN_DIM + d];
    #pragma unroll
    for (int hh=0;hh<H_;hh++){
      float sc = elr[sn*16+hh] + elr[n*16+8+hh];
      sc = sc>0.f? sc : 0.2f*sc;
      float a = __expf(sc - s_m[w][hh]) * s_is[w][hh];
      acc[hh]=fmaf(a,xv,acc[hh]);
    }
  }
  #pragma unroll
  for (int hh=0;hh<H_;hh++) acc[hh] += __shfl_xor(acc[hh],32,64);
  if (hw==0){
    #pragma unroll
    for (int hh=0;hh<H_;hh++) hagg[((size_t)n*H_+hh)*D_ + d] = acc[hh];
  }
}

// ---------------- h1 = relu(hagg @ blockdiag(W0) + b0) -> bf16, one wave per node ----------------

__global__ __launch_bounds__(256) void k_gemm_h1(const float* __restrict__ hagg, const float* __restrict__ W0,
    const float* __restrict__ b0, unsigned short* __restrict__ h1b){
  __shared__ float s_hg[4][HD];   // [k*8+h] transposed layout
  int w = threadIdx.x>>6, lane = threadIdx.x&63;
  int n = blockIdx.x*4 + w;
  {
    float4 v = *(const float4*)&hagg[(size_t)n*HD + lane*4];
    int h = lane>>3, k0 = (lane*4)&31;
    s_hg[w][(k0+0)*8+h]=v.x; s_hg[w][(k0+1)*8+h]=v.y;
    s_hg[w][(k0+2)*8+h]=v.z; s_hg[w][(k0+3)*8+h]=v.w;
  }
  __syncthreads();
  int col0 = lane*4;
  int h = lane>>3;
  float4 acc = make_float4(0,0,0,0);
  #pragma unroll 8
  for (int k=0;k<IN_DIM;k++){
    float hv = s_hg[w][k*8+h];
    float4 wv = *(const float4*)&W0[(size_t)k*HD + col0];
    acc.x=fmaf(hv,wv.x,acc.x); acc.y=fmaf(hv,wv.y,acc.y);
    acc.z=fmaf(hv,wv.z,acc.z); acc.w=fmaf(hv,wv.w,acc.w);
  }
  float4 bv = *(const float4*)&b0[col0];
  ushort4 us;
  us.x = f2b(fmaxf(acc.x+bv.x,0.f));
  us.y = f2b(fmaxf(acc.y+bv.y,0.f));
  us.z = f2b(fmaxf(acc.z+bv.z,0.f));
  us.w = f2b(fmaxf(acc.w+bv.w,0.f));
  *(ushort4*)&h1b[(size_t)n*HD + col0] = us;
}

// ---------------- feat1 = h1b @ W1 via MFMA; output bf16 ----------------
// block=4 waves, 64 rows; wave: 16 rows x 256 cols; K=256 in 8 steps of 32.
// A frag: lane holds h1b[row=base+(lane&15)][k=ks*32+8*(lane>>4)..+7]  (16B load)
// B frag: pre-packed Wp, lane-contiguous 16B
// C/D: col=lane&15, row=4*(lane>>4)+reg  [verified m89/m91]

__global__ __launch_bounds__(256) void k_gemm1_mfma(const unsigned short* __restrict__ h1b,
    const unsigned short* __restrict__ Wp, unsigned short* __restrict__ featb){
  int wv = threadIdx.x>>6, lane = threadIdx.x&63;
  int arow = blockIdx.x*64 + wv*16 + (lane&15);
  if (arow >= N_NODES) arow = N_NODES-1;       // clamp reads; writes guarded below
  int kgrp = lane>>4;
  f32x4 acc[16];
  #pragma unroll
  for (int nt=0;nt<16;nt++) acc[nt]=(f32x4){0.f,0.f,0.f,0.f};
  const unsigned short* aptr = h1b + (size_t)arow*HD + kgrp*8;
  #pragma unroll
  for (int ks=0; ks<8; ks++){
    bf16x8 a = *(const bf16x8*)(aptr + ks*32);
    #pragma unroll
    for (int nt=0; nt<16; nt++){
      bf16x8 b = *(const bf16x8*)(Wp + (((ks*16+nt)*64+lane)<<3));
      acc[nt] = __builtin_amdgcn_mfma_f32_16x16x32_bf16(a, b, acc[nt], 0, 0, 0);
    }
  }
  int rbase = blockIdx.x*64 + wv*16 + (lane>>4)*4;
  int col = lane&15;
  #pragma unroll
  for (int nt=0;nt<16;nt++){
    #pragma unroll
    for (int r=0;r<4;r++){
      int row = rbase+r;
      if (row<N_NODES) featb[(size_t)row*HD + nt*16+col] = f2b(acc[nt][r]);
    }
  }
}

// ---------------- layer-1 edge softmax + aggregate + head-mean (bf16 feat gather) ----------------

__global__ __launch_bounds__(256) void k_agg1(const int* __restrict__ offs, const int* __restrict__ csr_src,
   const int* __restrict__ csr_eid, const unsigned short* __restrict__ featb, const float* __restrict__ elr,
   const float* __restrict__ bias, float* __restrict__ out, float* __restrict__ alpha_out){
  __shared__ float s_al[4][ECAP][H_];
  __shared__ int   s_sn[4][ECAP];
  __shared__ int   s_eid[4][ECAP];
  int w = threadIdx.x>>6, lane = threadIdx.x&63;
  int n = blockIdx.x*4 + w;
  int h = lane>>3, sub = lane&7;
  int off = offs[n], deg = offs[n+1]-off;
  float er_n = elr[n*16 + 8 + h];

  float m=-1e30f, s=0.f;
  for (int i=sub; i<deg; i+=8){
    int p = off+i;
    int sn = csr_src[p];
    float sc = elr[sn*16+h] + er_n;
    sc = sc>0.f? sc : 0.2f*sc;
    if (i<ECAP){
      s_al[w][i][h]=sc;
      if (h==0){ s_sn[w][i]=sn; s_eid[w][i]=csr_eid[p]; }
    }
    float mn = fmaxf(m,sc);
    s = s*__expf(m-mn) + __expf(sc-mn);
    m = mn;
  }
  #pragma unroll
  for (int o=4;o>=1;o>>=1){
    float m2=__shfl_xor(m,o,64), s2=__shfl_xor(s,o,64);
    float mn=fmaxf(m,m2);
    s = s*__expf(m-mn) + s2*__expf(m2-mn);
    m = mn;
  }
  float inv_s = (s>0.f)? 1.f/s : 0.f;
  int dcap = deg<ECAP? deg:ECAP;
  __syncthreads();
  for (int i=sub; i<dcap; i+=8){
    float a = __expf(s_al[w][i][h]-m)*inv_s;
    s_al[w][i][h] = a;
    alpha_out[(size_t)s_eid[w][i]*H_ + h] = a;
  }
  __syncthreads();

  int d0 = 4*lane;
  float4 acc0 = make_float4(0,0,0,0), acc1 = make_float4(0,0,0,0);
  int i=0;
  for (; i+4<=dcap; i+=4){
    int sn0=s_sn[w][i], sn1=s_sn[w][i+1], sn2=s_sn[w][i+2], sn3=s_sn[w][i+3];
    float a0=s_al[w][i  ][h];
    float a1=s_al[w][i+1][h];
    float a2=s_al[w][i+2][h];
    float a3=s_al[w][i+3][h];
    ushort4 u0=*(const ushort4*)&featb[(size_t)sn0*HD+d0];
    ushort4 u1=*(const ushort4*)&featb[(size_t)sn1*HD+d0];
    ushort4 u2=*(const ushort4*)&featb[(size_t)sn2*HD+d0];
    ushort4 u3=*(const ushort4*)&featb[(size_t)sn3*HD+d0];
    acc0.x=fmaf(a0,b2f(u0.x),acc0.x); acc0.y=fmaf(a0,b2f(u0.y),acc0.y); acc0.z=fmaf(a0,b2f(u0.z),acc0.z); acc0.w=fmaf(a0,b2f(u0.w),acc0.w);
    acc1.x=fmaf(a1,b2f(u1.x),acc1.x); acc1.y=fmaf(a1,b2f(u1.y),acc1.y); acc1.z=fmaf(a1,b2f(u1.z),acc1.z); acc1.w=fmaf(a1,b2f(u1.w),acc1.w);
    acc0.x=fmaf(a2,b2f(u2.x),acc0.x); acc0.y=fmaf(a2,b2f(u2.y),acc0.y); acc0.z=fmaf(a2,b2f(u2.z),acc0.z); acc0.w=fmaf(a2,b2f(u2.w),acc0.w);
    acc1.x=fmaf(a3,b2f(u3.x),acc1.x); acc1.y=fmaf(a3,b2f(u3.y),acc1.y); acc1.z=fmaf(a3,b2f(u3.z),acc1.z); acc1.w=fmaf(a3,b2f(u3.w),acc1.w);
  }
  for (; i<dcap; ++i){
    int sn = s_sn[w][i];
    float a=s_al[w][i][h];
    ushort4 u=*(const ushort4*)&featb[(size_t)sn*HD+d0];
    acc0.x=fmaf(a,b2f(u.x),acc0.x); acc0.y=fmaf(a,b2f(u.y),acc0.y); acc0.z=fmaf(a,b2f(u.z),acc0.z); acc0.w=fmaf(a,b2f(u.w),acc0.w);
  }
  for (; i<deg; ++i){            // rare tail: deg > ECAP
    int p = off+i;
    int sn = csr_src[p];
    float sc = elr[sn*16+h] + er_n;
    sc = sc>0.f? sc : 0.2f*sc;
    float a=__expf(sc-m)*inv_s;
    ushort4 u=*(const ushort4*)&featb[(size_t)sn*HD+d0];
    acc0.x=fmaf(a,b2f(u.x),acc0.x); acc0.y=fmaf(a,b2f(u.y),acc0.y); acc0.z=fmaf(a,b2f(u.z),acc0.z); acc0.w=fmaf(a,b2f(u.w),acc0.w);
    if (sub==0) alpha_out[(size_t)csr_eid[p]*H_+h]=a;
  }

  float4 v;
  v.x = acc0.x+acc1.x + bias[d0+0];
  v.y = acc0.y+acc1.y + bias[d0+1];
  v.z = acc0.z+acc1.z + bias[d0+2];
  v.w = acc0.w+acc1.w + bias[d0+3];
  #pragma unroll
  for (int o=8;o<64;o<<=1){
    v.x+=__shfl_xor(v.x,o,64);
    v.y+=__shfl_xor(v.y,o,64);
    v.z+=__shfl_xor(v.z,o,64);
    v.w+=__shfl_xor(v.w,o,64);
  }
  if (h==0){
    v.x*=0.125f; v.y*=0.125f; v.z*=0.125f; v.w*=0.125f;
    *(float4*)&out[(size_t)n*D_+4*sub] = v;
  }
}

// ---------------- launcher ----------------

extern "C" void kernel_launch(void* const* d_in, const int* in_sizes, int n_in,
                              void* d_out, int out_size, void* d_ws, size_t ws_size,
                              hipStream_t stream){
  const float* h   = (const float*)d_in[0];
  const int*   src = (const int*)d_in[1];
  const int*   dst = (const int*)d_in[2];
  const float* W0  = (const float*)d_in[3];
  const float* al0 = (const float*)d_in[4];
  const float* ar0 = (const float*)d_in[5];
  const float* b0  = (const float*)d_in[6];
  const float* W1  = (const float*)d_in[7];
  const float* al1 = (const float*)d_in[8];
  const float* ar1 = (const float*)d_in[9];
  const float* b1  = (const float*)d_in[10];
  float* out_final = (float*)d_out;
  float* alpha_out = (float*)d_out + (size_t)N_NODES*D_;

  char* wsp = (char*)d_ws;
  auto alloc=[&](size_t bytes)->char*{ char* p=wsp; wsp += (bytes+255)&~size_t(255); return p; };
  int*   deg     = (int*)alloc((size_t)N_NODES*4);
  int*   offs    = (int*)alloc((size_t)(N_NODES+1)*4);
  int*   cursor  = (int*)alloc((size_t)N_NODES*4);
  int*   bsums   = (int*)alloc(1024);
  int*   csr_src = (int*)alloc((size_t)N_EDGES*4);
  int*   csr_eid = (int*)alloc((size_t)N_EDGES*4);
  float* bufA    = (float*)alloc((size_t)N_NODES*HD*4);   // hagg (f32), later featb (bf16)
  unsigned short* h1b = (unsigned short*)alloc((size_t)N_NODES*HD*2);
  float* elr0    = (float*)alloc((size_t)N_NODES*16*4);
  float* elr1    = (float*)alloc((size_t)N_NODES*16*4);
  float* Wa0     = (float*)alloc((size_t)IN_DIM*16*4);
  float* Wa1     = (float*)alloc((size_t)HD*16*4);
  unsigned short* W1p = (unsigned short*)alloc((size_t)HD*HD*2);
  float* hagg    = bufA;
  unsigned short* featb = (unsigned short*)bufA;  // reuse: hagg dead after k_gemm_h1

  hipMemsetAsync(deg, 0, (size_t)N_NODES*4, stream);
  int eb = (N_EDGES+255)/256;
  int nbchunks = (N_NODES+255)/256;
  k_hist       <<<eb,      256,0,stream>>>(dst, deg);
  k_block_sums <<<nbchunks,256,0,stream>>>(deg, bsums);
  k_scan_bsums <<<1,       64, 0,stream>>>(bsums, nbchunks);
  k_scan_chunks<<<nbchunks,256,0,stream>>>(deg, bsums, offs, cursor);
  k_scatter    <<<eb,      256,0,stream>>>(src, dst, cursor, csr_src, csr_eid);

  k_prep<IN_DIM><<<1,256,0,stream>>>(W0, al0, ar0, Wa0);
  k_prep<HD>    <<<8,256,0,stream>>>(W1, al1, ar1, Wa1);
  k_pack_w1     <<<256,256,0,stream>>>(W1, W1p);

  k_el<IN_DIM><<<N_NODES/16,256,0,stream>>>(h, Wa0, elr0);
  k_agg0      <<<N_NODES/4, 256,0,stream>>>(offs, csr_src, h, elr0, hagg);
  k_gemm_h1   <<<N_NODES/4, 256,0,stream>>>(hagg, W0, b0, h1b);
  k_el_bf16   <<<N_NODES/16,256,0,stream>>>(h1b, Wa1, elr1);
  k_gemm1_mfma<<<(N_NODES+63)/64,256,0,stream>>>(h1b, W1p, featb);
  k_agg1      <<<N_NODES/4, 256,0,stream>>>(offs, csr_src, csr_eid, featb, elr1, b1, out_final, alpha_out);
}

// Round 6
// 339.530 us; speedup vs baseline: 2.4746x; 1.1408x over previous
//
#include <hip/hip_runtime.h>

#define N_NODES 50000
#define N_EDGES 800000
#define IN_DIM 32
#define HD 256   // H*D
#define H_ 8
#define D_ 32
#define ECAP 64  // edges stashed in LDS per node (recompute tail beyond)
#define NT 17    // 16 W1 col-tiles + 1 Wa1 tile (el/er)

typedef __attribute__((ext_vector_type(8))) short bf16x8;
typedef __attribute__((ext_vector_type(4))) float f32x4;
typedef __attribute__((ext_vector_type(8))) unsigned short u16x8;

__device__ inline unsigned short f2b(float f){
  union{float f;unsigned int u;}v; v.f=f;
  unsigned int r=(v.u + 0x7FFFu + ((v.u>>16)&1u))>>16;
  return (unsigned short)r;
}
__device__ inline float b2f(unsigned short u){
  union{float f;unsigned int u32;}v; v.u32=((unsigned int)u)<<16; return v.f;
}

// ---------------- CSR build ----------------

__global__ void k_hist(const int* __restrict__ dst, int* __restrict__ deg){
  int e = blockIdx.x*256+threadIdx.x;
  if (e < N_EDGES) atomicAdd(&deg[dst[e]], 1);
}

__global__ void k_block_sums(const int* __restrict__ deg, int* __restrict__ bsums){
  int i = blockIdx.x*256+threadIdx.x;
  int v = (i<N_NODES)? deg[i]:0;
  #pragma unroll
  for (int o=32;o>=1;o>>=1) v += __shfl_xor(v,o,64);
  __shared__ int ws[4];
  if ((threadIdx.x&63)==0) ws[threadIdx.x>>6]=v;
  __syncthreads();
  if (threadIdx.x==0) bsums[blockIdx.x]=ws[0]+ws[1]+ws[2]+ws[3];
}

__global__ void k_scan_bsums(int* bsums, int nb){
  if (threadIdx.x==0 && blockIdx.x==0){
    int a=0;
    for (int i=0;i<nb;i++){int t=bsums[i]; bsums[i]=a; a+=t;}
  }
}

__device__ inline int wave_incl_scan(int v){
  int lane = threadIdx.x & 63;
  #pragma unroll
  for (int o=1;o<64;o<<=1){
    int t = __shfl_up(v,o,64);
    if (lane>=o) v+=t;
  }
  return v;
}

__global__ void k_scan_chunks(const int* __restrict__ deg, const int* __restrict__ bsums,
                              int* __restrict__ offs, int* __restrict__ cursor){
  int i = blockIdx.x*256+threadIdx.x;
  int v = (i<N_NODES)? deg[i]:0;
  int incl = wave_incl_scan(v);
  __shared__ int ws[4];
  int wid=threadIdx.x>>6, lane=threadIdx.x&63;
  if (lane==63) ws[wid]=incl;
  __syncthreads();
  if (threadIdx.x==0){int a=0; for(int w=0;w<4;w++){int t=ws[w];ws[w]=a;a+=t;}}
  __syncthreads();
  int excl = incl - v + ws[wid] + bsums[blockIdx.x];
  if (i<N_NODES){ offs[i]=excl; cursor[i]=excl; }
  if (i==N_NODES-1) offs[N_NODES]=excl+v;
}

__global__ void k_scatter(const int* __restrict__ src, const int* __restrict__ dst,
                          int* __restrict__ cursor, int* __restrict__ csr_src,
                          int* __restrict__ csr_eid){
  int e = blockIdx.x*256+threadIdx.x;
  if (e<N_EDGES){
    int d = dst[e];
    int pos = atomicAdd(&cursor[d],1);
    csr_src[pos]=src[e];
    csr_eid[pos]=e;
  }
}

// ---------------- Wa precompute: Wa[k][h]=sum_d W[k][h*32+d]*al[h][d] (h<8), ar for h>=8 ----------------

template<int K>
__global__ void k_prep(const float* __restrict__ W, const float* __restrict__ al,
                       const float* __restrict__ ar, float* __restrict__ Wa){
  int t = blockIdx.x*256 + threadIdx.x;
  int k = t>>3, hh = t&7;
  if (k < K){
    float sl=0.f, sr=0.f;
    #pragma unroll
    for (int d=0; d<32; d++){
      float w = W[(size_t)k*HD + hh*32 + d];
      sl = fmaf(w, al[hh*32+d], sl);
      sr = fmaf(w, ar[hh*32+d], sr);
    }
    Wa[k*16 + hh]     = sl;
    Wa[k*16 + 8 + hh] = sr;
  }
}

// ---------------- fragment pack: 16 tiles of W1 + 1 tile of Wa1 ----------------
// Wp[((ks*NT+nt)*64+lane)*8+j] = bf16 of B[k=ks*32+8*(lane>>4)+j][col]; col=nt*16+(lane&15) or Wa1 col

__global__ void k_pack_w(const float* __restrict__ W, const float* __restrict__ Wa1,
                         unsigned short* __restrict__ Wp){
  int t = blockIdx.x*256+threadIdx.x;   // 8*NT*64*8 = 69632 total
  if (t >= 8*NT*64*8) return;
  int j=t&7, lane=(t>>3)&63;
  int g=t>>9; int nt=g%NT, ks=g/NT;
  int k = ks*32 + (lane>>4)*8 + j;
  float v;
  if (nt<16) v = W[(size_t)k*HD + nt*16 + (lane&15)];
  else       v = Wa1[k*16 + (lane&15)];
  Wp[t] = f2b(v);
}

// ---------------- el/er (layer 0, f32 input K=32): elr[n*16+j] = sum_k x[n,k]*Wa[k,j] ----------------

template<int K>
__global__ __launch_bounds__(256) void k_el(const float* __restrict__ x, const float* __restrict__ Wa,
                                            float* __restrict__ elr){
  __shared__ float sWa[K*16];
  __shared__ float sx[16][K+1];
  int tid = threadIdx.x;
  int nb = blockIdx.x*16;
  for (int i = tid; i < K*16; i += 256) sWa[i] = Wa[i];
  for (int i = tid; i < 16*K; i += 256){
    int r = i / K, c = i % K;
    sx[r][c] = x[(size_t)(nb+r)*K + c];
  }
  __syncthreads();
  int node = tid>>4, j = tid&15;
  float s = 0.f;
  #pragma unroll 8
  for (int k=0;k<K;k++) s = fmaf(sx[node][k], sWa[k*16+j], s);
  elr[(size_t)(nb+node)*16 + j] = s;
}

// ---------------- FUSED layer-0: edge softmax + aggregate raw x + blockdiag GEMM + ReLU -> h1b ----------------
// one wave per node. phase A: (h=lane>>3, sub=lane&7). phase B: (hw=lane>>5, d=lane&31).
// epilogue: transpose hagg via LDS (stride 9), then h1[col0..+3] per lane, relu, bf16 store.

__global__ __launch_bounds__(256) void k_agg0f(const int* __restrict__ offs, const int* __restrict__ csr_src,
    const float* __restrict__ x, const float* __restrict__ elr,
    const float* __restrict__ W0, const float* __restrict__ b0,
    unsigned short* __restrict__ h1b){
  __shared__ float s_al[4][ECAP][H_];
  __shared__ int   s_sn[4][ECAP];
  __shared__ float s_m[4][H_], s_is[4][H_];
  __shared__ float s_hg[4][32*9];      // transposed hagg, stride 9 (bank-spread)
  int w = threadIdx.x>>6, lane = threadIdx.x&63;
  int n = blockIdx.x*4 + w;
  int h = lane>>3, sub = lane&7;
  int off = offs[n], deg = offs[n+1]-off;
  float er_n = elr[n*16 + 8 + h];

  // ---- phase A: scores -> LDS, online (m,s) ----
  float m=-1e30f, s=0.f;
  for (int i=sub; i<deg; i+=8){
    int sn = csr_src[off+i];
    float sc = elr[sn*16+h] + er_n;
    sc = sc>0.f? sc : 0.2f*sc;
    if (i<ECAP){ s_al[w][i][h] = sc; if (h==0) s_sn[w][i] = sn; }
    float mn = fmaxf(m,sc);
    s = s*__expf(m-mn) + __expf(sc-mn);
    m = mn;
  }
  #pragma unroll
  for (int o=4;o>=1;o>>=1){
    float m2=__shfl_xor(m,o,64), s2=__shfl_xor(s,o,64);
    float mn=fmaxf(m,m2);
    s = s*__expf(m-mn)+s2*__expf(m2-mn); m=mn;
  }
  float inv_s = (s>0.f)?1.f/s:0.f;
  if (sub==0){ s_m[w][h]=m; s_is[w][h]=inv_s; }
  int dcap = deg<ECAP? deg:ECAP;
  for (int i=sub; i<dcap; i+=8)
    s_al[w][i][h] = __expf(s_al[w][i][h]-m)*inv_s;
  __syncthreads();

  // ---- phase B: aggregate x per head, 2 edges/step (hw split), 2x unroll ----
  int hw = lane>>5, d = lane&31;
  float acc[H_]  = {0,0,0,0,0,0,0,0};
  float accB[H_] = {0,0,0,0,0,0,0,0};
  int i = hw;
  for (; i+4<=dcap; i+=4){
    int snA = s_sn[w][i], snB = s_sn[w][i+2];
    float xvA = x[(size_t)snA*IN_DIM + d];
    float xvB = x[(size_t)snB*IN_DIM + d];
    float4 a0 = *(const float4*)&s_al[w][i][0];
    float4 a1 = *(const float4*)&s_al[w][i][4];
    float4 b0v = *(const float4*)&s_al[w][i+2][0];
    float4 b1v = *(const float4*)&s_al[w][i+2][4];
    acc[0]=fmaf(a0.x,xvA,acc[0]); acc[1]=fmaf(a0.y,xvA,acc[1]);
    acc[2]=fmaf(a0.z,xvA,acc[2]); acc[3]=fmaf(a0.w,xvA,acc[3]);
    acc[4]=fmaf(a1.x,xvA,acc[4]); acc[5]=fmaf(a1.y,xvA,acc[5]);
    acc[6]=fmaf(a1.z,xvA,acc[6]); acc[7]=fmaf(a1.w,xvA,acc[7]);
    accB[0]=fmaf(b0v.x,xvB,accB[0]); accB[1]=fmaf(b0v.y,xvB,accB[1]);
    accB[2]=fmaf(b0v.z,xvB,accB[2]); accB[3]=fmaf(b0v.w,xvB,accB[3]);
    accB[4]=fmaf(b1v.x,xvB,accB[4]); accB[5]=fmaf(b1v.y,xvB,accB[5]);
    accB[6]=fmaf(b1v.z,xvB,accB[6]); accB[7]=fmaf(b1v.w,xvB,accB[7]);
  }
  for (; i<dcap; i+=2){
    int sn = s_sn[w][i];
    float xv = x[(size_t)sn*IN_DIM + d];
    float4 a0 = *(const float4*)&s_al[w][i][0];
    float4 a1 = *(const float4*)&s_al[w][i][4];
    acc[0]=fmaf(a0.x,xv,acc[0]); acc[1]=fmaf(a0.y,xv,acc[1]);
    acc[2]=fmaf(a0.z,xv,acc[2]); acc[3]=fmaf(a0.w,xv,acc[3]);
    acc[4]=fmaf(a1.x,xv,acc[4]); acc[5]=fmaf(a1.y,xv,acc[5]);
    acc[6]=fmaf(a1.z,xv,acc[6]); acc[7]=fmaf(a1.w,xv,acc[7]);
  }
  for (; i<deg; i+=2){                    // rare tail: recompute
    int sn = csr_src[off+i];
    float xv = x[(size_t)sn*IN_DIM + d];
    #pragma unroll
    for (int hh=0;hh<H_;hh++){
      float sc = elr[sn*16+hh] + elr[n*16+8+hh];
      sc = sc>0.f? sc : 0.2f*sc;
      float a = __expf(sc - s_m[w][hh]) * s_is[w][hh];
      acc[hh]=fmaf(a,xv,acc[hh]);
    }
  }
  #pragma unroll
  for (int hh=0;hh<H_;hh++){
    acc[hh] += accB[hh];
    acc[hh] += __shfl_xor(acc[hh],32,64);
  }
  if (hw==0){
    #pragma unroll
    for (int hh=0;hh<H_;hh++) s_hg[w][d*9+hh] = acc[hh];
  }
  __syncthreads();

  // ---- epilogue: h1[col] = relu(sum_k hagg[h,k]*W0[k][col] + b0[col]) -> bf16 ----
  int col0 = lane*4;
  int h2 = lane>>3;            // col0/32
  float4 g = make_float4(0,0,0,0);
  #pragma unroll 8
  for (int k=0;k<IN_DIM;k++){
    float hv = s_hg[w][k*9+h2];
    float4 wv = *(const float4*)&W0[(size_t)k*HD + col0];
    g.x=fmaf(hv,wv.x,g.x); g.y=fmaf(hv,wv.y,g.y);
    g.z=fmaf(hv,wv.z,g.z); g.w=fmaf(hv,wv.w,g.w);
  }
  float4 bv = *(const float4*)&b0[col0];
  ushort4 us;
  us.x = f2b(fmaxf(g.x+bv.x,0.f));
  us.y = f2b(fmaxf(g.y+bv.y,0.f));
  us.z = f2b(fmaxf(g.z+bv.z,0.f));
  us.w = f2b(fmaxf(g.w+bv.w,0.f));
  *(ushort4*)&h1b[(size_t)n*HD + col0] = us;
}

// ---------------- feat1 = h1b @ [W1 | Wa1] via MFMA; featb bf16 + elr1 f32 ----------------

__global__ __launch_bounds__(256) void k_gemm1_mfma(const unsigned short* __restrict__ h1b,
    const unsigned short* __restrict__ Wp, unsigned short* __restrict__ featb,
    float* __restrict__ elr1){
  int wv = threadIdx.x>>6, lane = threadIdx.x&63;
  int arow = blockIdx.x*64 + wv*16 + (lane&15);
  if (arow >= N_NODES) arow = N_NODES-1;       // clamp reads; writes guarded below
  int kgrp = lane>>4;
  f32x4 acc[NT];
  #pragma unroll
  for (int nt=0;nt<NT;nt++) acc[nt]=(f32x4){0.f,0.f,0.f,0.f};
  const unsigned short* aptr = h1b + (size_t)arow*HD + kgrp*8;
  #pragma unroll
  for (int ks=0; ks<8; ks++){
    bf16x8 a = *(const bf16x8*)(aptr + ks*32);
    #pragma unroll
    for (int nt=0; nt<NT; nt++){
      bf16x8 b = *(const bf16x8*)(Wp + (((ks*NT+nt)*64+lane)<<3));
      acc[nt] = __builtin_amdgcn_mfma_f32_16x16x32_bf16(a, b, acc[nt], 0, 0, 0);
    }
  }
  int rbase = blockIdx.x*64 + wv*16 + (lane>>4)*4;
  int col = lane&15;
  #pragma unroll
  for (int nt=0;nt<16;nt++){
    #pragma unroll
    for (int r=0;r<4;r++){
      int row = rbase+r;
      if (row<N_NODES) featb[(size_t)row*HD + nt*16+col] = f2b(acc[nt][r]);
    }
  }
  #pragma unroll
  for (int r=0;r<4;r++){
    int row = rbase+r;
    if (row<N_NODES) elr1[(size_t)row*16 + col] = acc[16][r];
  }
}

// ---------------- layer-1 edge softmax + aggregate + head-mean (bf16 gather, 16B/lane) ----------------
// phase A: (h=lane>>3, sub=lane&7). phase B: (hw=lane>>5 edge parity, dl=lane&31 -> cols dl*8..+7, head=dl>>2)

__global__ __launch_bounds__(256) void k_agg1(const int* __restrict__ offs, const int* __restrict__ csr_src,
   const int* __restrict__ csr_eid, const unsigned short* __restrict__ featb, const float* __restrict__ elr,
   const float* __restrict__ bias, float* __restrict__ out, float* __restrict__ alpha_out){
  __shared__ float s_al[4][ECAP][H_];
  __shared__ int   s_sn[4][ECAP];
  __shared__ int   s_eid[4][ECAP];
  __shared__ float s_m[4][H_], s_is[4][H_];
  int w = threadIdx.x>>6, lane = threadIdx.x&63;
  int n = blockIdx.x*4 + w;
  int h = lane>>3, sub = lane&7;
  int off = offs[n], deg = offs[n+1]-off;
  float er_n = elr[n*16 + 8 + h];

  float m=-1e30f, s=0.f;
  for (int i=sub; i<deg; i+=8){
    int p = off+i;
    int sn = csr_src[p];
    float sc = elr[sn*16+h] + er_n;
    sc = sc>0.f? sc : 0.2f*sc;
    if (i<ECAP){
      s_al[w][i][h]=sc;
      if (h==0){ s_sn[w][i]=sn; s_eid[w][i]=csr_eid[p]; }
    }
    float mn = fmaxf(m,sc);
    s = s*__expf(m-mn) + __expf(sc-mn);
    m = mn;
  }
  #pragma unroll
  for (int o=4;o>=1;o>>=1){
    float m2=__shfl_xor(m,o,64), s2=__shfl_xor(s,o,64);
    float mn=fmaxf(m,m2);
    s = s*__expf(m-mn) + s2*__expf(m2-mn);
    m = mn;
  }
  float inv_s = (s>0.f)? 1.f/s : 0.f;
  if (sub==0){ s_m[w][h]=m; s_is[w][h]=inv_s; }
  int dcap = deg<ECAP? deg:ECAP;
  __syncthreads();
  for (int i=sub; i<dcap; i+=8){
    float a = __expf(s_al[w][i][h]-m)*inv_s;
    s_al[w][i][h] = a;
    alpha_out[(size_t)s_eid[w][i]*H_ + h] = a;
  }
  __syncthreads();

  // ---- phase B ----
  int hw = lane>>5, dl = lane&31;
  int c0 = dl*8;               // global cols c0..c0+7
  int hd = dl>>2;              // head of these cols
  float acc[8] = {0,0,0,0,0,0,0,0};
  float acc2[8] = {0,0,0,0,0,0,0,0};
  int i = hw;
  for (; i+8<=dcap; i+=8){
    int sn0=s_sn[w][i], sn1=s_sn[w][i+2], sn2=s_sn[w][i+4], sn3=s_sn[w][i+6];
    float a0=s_al[w][i  ][hd];
    float a1=s_al[w][i+2][hd];
    float a2=s_al[w][i+4][hd];
    float a3=s_al[w][i+6][hd];
    u16x8 u0=*(const u16x8*)&featb[(size_t)sn0*HD+c0];
    u16x8 u1=*(const u16x8*)&featb[(size_t)sn1*HD+c0];
    u16x8 u2=*(const u16x8*)&featb[(size_t)sn2*HD+c0];
    u16x8 u3=*(const u16x8*)&featb[(size_t)sn3*HD+c0];
    #pragma unroll
    for (int q=0;q<8;q++){
      acc[q] =fmaf(a0,b2f(u0[q]),acc[q]);
      acc2[q]=fmaf(a1,b2f(u1[q]),acc2[q]);
      acc[q] =fmaf(a2,b2f(u2[q]),acc[q]);
      acc2[q]=fmaf(a3,b2f(u3[q]),acc2[q]);
    }
  }
  for (; i<dcap; i+=2){
    int sn = s_sn[w][i];
    float a=s_al[w][i][hd];
    u16x8 u=*(const u16x8*)&featb[(size_t)sn*HD+c0];
    #pragma unroll
    for (int q=0;q<8;q++) acc[q]=fmaf(a,b2f(u[q]),acc[q]);
  }
  for (; i<deg; i+=2){           // rare tail: deg > ECAP
    int p = off+i;
    int sn = csr_src[p];
    float sc = elr[sn*16+hd] + elr[n*16+8+hd];
    sc = sc>0.f? sc : 0.2f*sc;
    float a=__expf(sc-s_m[w][hd])*s_is[w][hd];
    u16x8 u=*(const u16x8*)&featb[(size_t)sn*HD+c0];
    #pragma unroll
    for (int q=0;q<8;q++) acc[q]=fmaf(a,b2f(u[q]),acc[q]);
    if ((dl&3)==0) alpha_out[(size_t)csr_eid[p]*H_+hd]=a;
  }

  // combine hw halves, add bias, mean over heads
  #pragma unroll
  for (int q=0;q<8;q++){
    acc[q]+=acc2[q];
    acc[q]+=__shfl_xor(acc[q],32,64);
    acc[q]+=bias[c0+q];
  }
  #pragma unroll
  for (int o=4;o<32;o<<=1){
    #pragma unroll
    for (int q=0;q<8;q++) acc[q]+=__shfl_xor(acc[q],o,64);
  }
  if (hw==0 && dl<4){
    float4 o0 = make_float4(acc[0],acc[1],acc[2],acc[3]);
    float4 o1 = make_float4(acc[4],acc[5],acc[6],acc[7]);
    o0.x*=0.125f; o0.y*=0.125f; o0.z*=0.125f; o0.w*=0.125f;
    o1.x*=0.125f; o1.y*=0.125f; o1.z*=0.125f; o1.w*=0.125f;
    *(float4*)&out[(size_t)n*D_ + dl*8    ] = o0;
    *(float4*)&out[(size_t)n*D_ + dl*8 + 4] = o1;
  }
}

// ---------------- launcher ----------------

extern "C" void kernel_launch(void* const* d_in, const int* in_sizes, int n_in,
                              void* d_out, int out_size, void* d_ws, size_t ws_size,
                              hipStream_t stream){
  const float* h   = (const float*)d_in[0];
  const int*   src = (const int*)d_in[1];
  const int*   dst = (const int*)d_in[2];
  const float* W0  = (const float*)d_in[3];
  const float* al0 = (const float*)d_in[4];
  const float* ar0 = (const float*)d_in[5];
  const float* b0  = (const float*)d_in[6];
  const float* W1  = (const float*)d_in[7];
  const float* al1 = (const float*)d_in[8];
  const float* ar1 = (const float*)d_in[9];
  const float* b1  = (const float*)d_in[10];
  float* out_final = (float*)d_out;
  float* alpha_out = (float*)d_out + (size_t)N_NODES*D_;

  char* wsp = (char*)d_ws;
  auto alloc=[&](size_t bytes)->char*{ char* p=wsp; wsp += (bytes+255)&~size_t(255); return p; };
  int*   deg     = (int*)alloc((size_t)N_NODES*4);
  int*   offs    = (int*)alloc((size_t)(N_NODES+1)*4);
  int*   cursor  = (int*)alloc((size_t)N_NODES*4);
  int*   bsums   = (int*)alloc(1024);
  int*   csr_src = (int*)alloc((size_t)N_EDGES*4);
  int*   csr_eid = (int*)alloc((size_t)N_EDGES*4);
  unsigned short* featb = (unsigned short*)alloc((size_t)N_NODES*HD*2);
  unsigned short* h1b   = (unsigned short*)alloc((size_t)N_NODES*HD*2);
  float* elr0    = (float*)alloc((size_t)N_NODES*16*4);
  float* elr1    = (float*)alloc((size_t)N_NODES*16*4);
  float* Wa0     = (float*)alloc((size_t)IN_DIM*16*4);
  float* Wa1     = (float*)alloc((size_t)HD*16*4);
  unsigned short* Wp = (unsigned short*)alloc((size_t)8*NT*64*8*2);

  hipMemsetAsync(deg, 0, (size_t)N_NODES*4, stream);
  int eb = (N_EDGES+255)/256;
  int nbchunks = (N_NODES+255)/256;
  k_hist       <<<eb,      256,0,stream>>>(dst, deg);
  k_block_sums <<<nbchunks,256,0,stream>>>(deg, bsums);
  k_scan_bsums <<<1,       64, 0,stream>>>(bsums, nbchunks);
  k_scan_chunks<<<nbchunks,256,0,stream>>>(deg, bsums, offs, cursor);
  k_scatter    <<<eb,      256,0,stream>>>(src, dst, cursor, csr_src, csr_eid);

  k_prep<IN_DIM><<<1,256,0,stream>>>(W0, al0, ar0, Wa0);
  k_prep<HD>    <<<8,256,0,stream>>>(W1, al1, ar1, Wa1);
  k_pack_w      <<<(8*NT*64*8+255)/256,256,0,stream>>>(W1, Wa1, Wp);

  k_el<IN_DIM><<<N_NODES/16,256,0,stream>>>(h, Wa0, elr0);
  k_agg0f     <<<N_NODES/4, 256,0,stream>>>(offs, csr_src, h, elr0, W0, b0, h1b);
  k_gemm1_mfma<<<(N_NODES+63)/64,256,0,stream>>>(h1b, Wp, featb, elr1);
  k_agg1      <<<N_NODES/4, 256,0,stream>>>(offs, csr_src, csr_eid, featb, elr1, b1, out_final, alpha_out);
}

// Round 7
// 328.464 us; speedup vs baseline: 2.5580x; 1.0337x over previous
//
#include <hip/hip_runtime.h>

#define N_NODES 50000
#define N_EDGES 800000
#define IN_DIM 32
#define HD 256   // H*D
#define H_ 8
#define D_ 32
#define ECAP 64  // edges stashed in LDS per node (recompute tail beyond)
#define NT 17    // 16 W1 col-tiles + 1 Wa1 tile (el/er)

typedef __attribute__((ext_vector_type(8))) short bf16x8;
typedef __attribute__((ext_vector_type(4))) float f32x4;
typedef __attribute__((ext_vector_type(8))) unsigned short u16x8;

__device__ inline unsigned short f2b(float f){
  union{float f;unsigned int u;}v; v.f=f;
  unsigned int r=(v.u + 0x7FFFu + ((v.u>>16)&1u))>>16;
  return (unsigned short)r;
}
__device__ inline float b2f(unsigned short u){
  union{float f;unsigned int u32;}v; v.u32=((unsigned int)u)<<16; return v.f;
}

// ---------------- CSR build ----------------

__global__ void k_hist(const int* __restrict__ dst, int* __restrict__ deg){
  int e = blockIdx.x*256+threadIdx.x;
  if (e < N_EDGES) atomicAdd(&deg[dst[e]], 1);
}

__global__ void k_block_sums(const int* __restrict__ deg, int* __restrict__ bsums){
  int i = blockIdx.x*256+threadIdx.x;
  int v = (i<N_NODES)? deg[i]:0;
  #pragma unroll
  for (int o=32;o>=1;o>>=1) v += __shfl_xor(v,o,64);
  __shared__ int ws[4];
  if ((threadIdx.x&63)==0) ws[threadIdx.x>>6]=v;
  __syncthreads();
  if (threadIdx.x==0) bsums[blockIdx.x]=ws[0]+ws[1]+ws[2]+ws[3];
}

__global__ void k_scan_bsums(int* bsums, int nb){
  if (threadIdx.x==0 && blockIdx.x==0){
    int a=0;
    for (int i=0;i<nb;i++){int t=bsums[i]; bsums[i]=a; a+=t;}
  }
}

__device__ inline int wave_incl_scan(int v){
  int lane = threadIdx.x & 63;
  #pragma unroll
  for (int o=1;o<64;o<<=1){
    int t = __shfl_up(v,o,64);
    if (lane>=o) v+=t;
  }
  return v;
}

__global__ void k_scan_chunks(const int* __restrict__ deg, const int* __restrict__ bsums,
                              int* __restrict__ offs, int* __restrict__ cursor){
  int i = blockIdx.x*256+threadIdx.x;
  int v = (i<N_NODES)? deg[i]:0;
  int incl = wave_incl_scan(v);
  __shared__ int ws[4];
  int wid=threadIdx.x>>6, lane=threadIdx.x&63;
  if (lane==63) ws[wid]=incl;
  __syncthreads();
  if (threadIdx.x==0){int a=0; for(int w=0;w<4;w++){int t=ws[w];ws[w]=a;a+=t;}}
  __syncthreads();
  int excl = incl - v + ws[wid] + bsums[blockIdx.x];
  if (i<N_NODES){ offs[i]=excl; cursor[i]=excl; }
  if (i==N_NODES-1) offs[N_NODES]=excl+v;
}

__global__ void k_scatter(const int* __restrict__ src, const int* __restrict__ dst,
                          int* __restrict__ cursor, int* __restrict__ csr_src,
                          int* __restrict__ csr_eid){
  int e = blockIdx.x*256+threadIdx.x;
  if (e<N_EDGES){
    int d = dst[e];
    int pos = atomicAdd(&cursor[d],1);
    csr_src[pos]=src[e];
    csr_eid[pos]=e;
  }
}

// ---------------- Wa precompute: Wa[k][h]=sum_d W[k][h*32+d]*al[h][d] (h<8), ar for h>=8 ----------------

template<int K>
__global__ void k_prep(const float* __restrict__ W, const float* __restrict__ al,
                       const float* __restrict__ ar, float* __restrict__ Wa){
  int t = blockIdx.x*256 + threadIdx.x;
  int k = t>>3, hh = t&7;
  if (k < K){
    float sl=0.f, sr=0.f;
    #pragma unroll
    for (int d=0; d<32; d++){
      float w = W[(size_t)k*HD + hh*32 + d];
      sl = fmaf(w, al[hh*32+d], sl);
      sr = fmaf(w, ar[hh*32+d], sr);
    }
    Wa[k*16 + hh]     = sl;
    Wa[k*16 + 8 + hh] = sr;
  }
}

// ---------------- fragment pack: 16 tiles of W1 + 1 tile of Wa1 ----------------

__global__ void k_pack_w(const float* __restrict__ W, const float* __restrict__ Wa1,
                         unsigned short* __restrict__ Wp){
  int t = blockIdx.x*256+threadIdx.x;   // 8*NT*64*8 = 69632 total
  if (t >= 8*NT*64*8) return;
  int j=t&7, lane=(t>>3)&63;
  int g=t>>9; int nt=g%NT, ks=g/NT;
  int k = ks*32 + (lane>>4)*8 + j;
  float v;
  if (nt<16) v = W[(size_t)k*HD + nt*16 + (lane&15)];
  else       v = Wa1[k*16 + (lane&15)];
  Wp[t] = f2b(v);
}

// ---------------- W0 pack (bf16, k-major per col, coalesced u16x8):
// W0t[(kb*HD + c)*8 + q] = bf16(W0[(kb*8+q)*HD + c]),  kb=0..3, q=0..7, c=0..255

__global__ void k_pack_w0(const float* __restrict__ W0, unsigned short* __restrict__ W0t){
  int t = blockIdx.x*256+threadIdx.x;   // 8192 total
  if (t < 8192){
    int q = t&7, c = (t>>3)&255, kb = t>>11;
    W0t[t] = f2b(W0[(size_t)(kb*8+q)*HD + c]);
  }
}

// ---------------- el/er (layer 0, f32 input K=32): elr[n*16+j] = sum_k x[n,k]*Wa[k,j] ----------------

template<int K>
__global__ __launch_bounds__(256) void k_el(const float* __restrict__ x, const float* __restrict__ Wa,
                                            float* __restrict__ elr){
  __shared__ float sWa[K*16];
  __shared__ float sx[16][K+1];
  int tid = threadIdx.x;
  int nb = blockIdx.x*16;
  for (int i = tid; i < K*16; i += 256) sWa[i] = Wa[i];
  for (int i = tid; i < 16*K; i += 256){
    int r = i / K, c = i % K;
    sx[r][c] = x[(size_t)(nb+r)*K + c];
  }
  __syncthreads();
  int node = tid>>4, j = tid&15;
  float s = 0.f;
  #pragma unroll 8
  for (int k=0;k<K;k++) s = fmaf(sx[node][k], sWa[k*16+j], s);
  elr[(size_t)(nb+node)*16 + j] = s;
}

// ---------------- FUSED layer-0: edge softmax + aggregate raw x + blockdiag GEMM + ReLU -> h1b ----------------
// one wave per node for phases A/B; epilogue column-split: wave w -> cols [w*64,w*64+64) of ALL 4 nodes.

__global__ __launch_bounds__(256) void k_agg0f(const int* __restrict__ offs, const int* __restrict__ csr_src,
    const float* __restrict__ x, const float* __restrict__ elr,
    const unsigned short* __restrict__ W0t, const float* __restrict__ b0,
    unsigned short* __restrict__ h1b){
  __shared__ float s_al[4][ECAP][H_];
  __shared__ int   s_sn[4][ECAP];
  __shared__ float s_m[4][H_], s_is[4][H_];
  __shared__ float s_hg[4][32*9];      // transposed hagg, stride 9 (bank-spread)
  int w = threadIdx.x>>6, lane = threadIdx.x&63;
  int n = blockIdx.x*4 + w;
  int h = lane>>3, sub = lane&7;
  int off = offs[n], deg = offs[n+1]-off;
  float er_n = elr[n*16 + 8 + h];

  // ---- phase A: scores -> LDS, online (m,s) ----
  float m=-1e30f, s=0.f;
  for (int i=sub; i<deg; i+=8){
    int sn = csr_src[off+i];
    float sc = elr[sn*16+h] + er_n;
    sc = sc>0.f? sc : 0.2f*sc;
    if (i<ECAP){ s_al[w][i][h] = sc; if (h==0) s_sn[w][i] = sn; }
    float mn = fmaxf(m,sc);
    s = s*__expf(m-mn) + __expf(sc-mn);
    m = mn;
  }
  #pragma unroll
  for (int o=4;o>=1;o>>=1){
    float m2=__shfl_xor(m,o,64), s2=__shfl_xor(s,o,64);
    float mn=fmaxf(m,m2);
    s = s*__expf(m-mn)+s2*__expf(m2-mn); m=mn;
  }
  float inv_s = (s>0.f)?1.f/s:0.f;
  if (sub==0){ s_m[w][h]=m; s_is[w][h]=inv_s; }
  int dcap = deg<ECAP? deg:ECAP;
  for (int i=sub; i<dcap; i+=8)
    s_al[w][i][h] = __expf(s_al[w][i][h]-m)*inv_s;
  __syncthreads();

  // ---- phase B: aggregate x per head, 2 edges/step (hw split), 4x unroll (4 gathers in flight) ----
  int hw = lane>>5, d = lane&31;
  float acc[H_]  = {0,0,0,0,0,0,0,0};
  float accB[H_] = {0,0,0,0,0,0,0,0};
  int i = hw;
  for (; i+8<=dcap; i+=8){
    int snA = s_sn[w][i],   snB = s_sn[w][i+2];
    int snC = s_sn[w][i+4], snD = s_sn[w][i+6];
    float xvA = x[(size_t)snA*IN_DIM + d];
    float xvB = x[(size_t)snB*IN_DIM + d];
    float xvC = x[(size_t)snC*IN_DIM + d];
    float xvD = x[(size_t)snD*IN_DIM + d];
    float4 aA0 = *(const float4*)&s_al[w][i][0],   aA1 = *(const float4*)&s_al[w][i][4];
    float4 aB0 = *(const float4*)&s_al[w][i+2][0], aB1 = *(const float4*)&s_al[w][i+2][4];
    float4 aC0 = *(const float4*)&s_al[w][i+4][0], aC1 = *(const float4*)&s_al[w][i+4][4];
    float4 aD0 = *(const float4*)&s_al[w][i+6][0], aD1 = *(const float4*)&s_al[w][i+6][4];
    acc[0]=fmaf(aA0.x,xvA,acc[0]); acc[1]=fmaf(aA0.y,xvA,acc[1]);
    acc[2]=fmaf(aA0.z,xvA,acc[2]); acc[3]=fmaf(aA0.w,xvA,acc[3]);
    acc[4]=fmaf(aA1.x,xvA,acc[4]); acc[5]=fmaf(aA1.y,xvA,acc[5]);
    acc[6]=fmaf(aA1.z,xvA,acc[6]); acc[7]=fmaf(aA1.w,xvA,acc[7]);
    accB[0]=fmaf(aB0.x,xvB,accB[0]); accB[1]=fmaf(aB0.y,xvB,accB[1]);
    accB[2]=fmaf(aB0.z,xvB,accB[2]); accB[3]=fmaf(aB0.w,xvB,accB[3]);
    accB[4]=fmaf(aB1.x,xvB,accB[4]); accB[5]=fmaf(aB1.y,xvB,accB[5]);
    accB[6]=fmaf(aB1.z,xvB,accB[6]); accB[7]=fmaf(aB1.w,xvB,accB[7]);
    acc[0]=fmaf(aC0.x,xvC,acc[0]); acc[1]=fmaf(aC0.y,xvC,acc[1]);
    acc[2]=fmaf(aC0.z,xvC,acc[2]); acc[3]=fmaf(aC0.w,xvC,acc[3]);
    acc[4]=fmaf(aC1.x,xvC,acc[4]); acc[5]=fmaf(aC1.y,xvC,acc[5]);
    acc[6]=fmaf(aC1.z,xvC,acc[6]); acc[7]=fmaf(aC1.w,xvC,acc[7]);
    accB[0]=fmaf(aD0.x,xvD,accB[0]); accB[1]=fmaf(aD0.y,xvD,accB[1]);
    accB[2]=fmaf(aD0.z,xvD,accB[2]); accB[3]=fmaf(aD0.w,xvD,accB[3]);
    accB[4]=fmaf(aD1.x,xvD,accB[4]); accB[5]=fmaf(aD1.y,xvD,accB[5]);
    accB[6]=fmaf(aD1.z,xvD,accB[6]); accB[7]=fmaf(aD1.w,xvD,accB[7]);
  }
  for (; i<dcap; i+=2){
    int sn = s_sn[w][i];
    float xv = x[(size_t)sn*IN_DIM + d];
    float4 a0 = *(const float4*)&s_al[w][i][0];
    float4 a1 = *(const float4*)&s_al[w][i][4];
    acc[0]=fmaf(a0.x,xv,acc[0]); acc[1]=fmaf(a0.y,xv,acc[1]);
    acc[2]=fmaf(a0.z,xv,acc[2]); acc[3]=fmaf(a0.w,xv,acc[3]);
    acc[4]=fmaf(a1.x,xv,acc[4]); acc[5]=fmaf(a1.y,xv,acc[5]);
    acc[6]=fmaf(a1.z,xv,acc[6]); acc[7]=fmaf(a1.w,xv,acc[7]);
  }
  for (; i<deg; i+=2){                    // rare tail: recompute
    int sn = csr_src[off+i];
    float xv = x[(size_t)sn*IN_DIM + d];
    #pragma unroll
    for (int hh=0;hh<H_;hh++){
      float sc = elr[sn*16+hh] + elr[n*16+8+hh];
      sc = sc>0.f? sc : 0.2f*sc;
      float a = __expf(sc - s_m[w][hh]) * s_is[w][hh];
      acc[hh]=fmaf(a,xv,acc[hh]);
    }
  }
  #pragma unroll
  for (int hh=0;hh<H_;hh++){
    acc[hh] += accB[hh];
    acc[hh] += __shfl_xor(acc[hh],32,64);
  }
  if (hw==0){
    #pragma unroll
    for (int hh=0;hh<H_;hh++) s_hg[w][d*9+hh] = acc[hh];
  }
  __syncthreads();

  // ---- epilogue (column-split): wave w computes cols [w*64, w*64+64) for ALL 4 nodes ----
  int col = w*64 + lane;
  int hcol = col>>5;
  float a0=0.f, a1=0.f, a2=0.f, a3=0.f;
  #pragma unroll
  for (int kb=0;kb<4;kb++){
    u16x8 wv8 = *(const u16x8*)(W0t + ((size_t)(kb*HD + col)<<3));
    #pragma unroll
    for (int q=0;q<8;q++){
      float wv = b2f(wv8[q]);
      int k = kb*8+q;
      a0 = fmaf(s_hg[0][k*9+hcol], wv, a0);
      a1 = fmaf(s_hg[1][k*9+hcol], wv, a1);
      a2 = fmaf(s_hg[2][k*9+hcol], wv, a2);
      a3 = fmaf(s_hg[3][k*9+hcol], wv, a3);
    }
  }
  float bb = b0[col];
  int n0 = blockIdx.x*4;
  h1b[(size_t)(n0+0)*HD+col] = f2b(fmaxf(a0+bb,0.f));
  h1b[(size_t)(n0+1)*HD+col] = f2b(fmaxf(a1+bb,0.f));
  h1b[(size_t)(n0+2)*HD+col] = f2b(fmaxf(a2+bb,0.f));
  h1b[(size_t)(n0+3)*HD+col] = f2b(fmaxf(a3+bb,0.f));
}

// ---------------- feat1 = h1b @ [W1 | Wa1] via MFMA; featb bf16 + elr1 f32 ----------------

__global__ __launch_bounds__(256) void k_gemm1_mfma(const unsigned short* __restrict__ h1b,
    const unsigned short* __restrict__ Wp, unsigned short* __restrict__ featb,
    float* __restrict__ elr1){
  int wv = threadIdx.x>>6, lane = threadIdx.x&63;
  int arow = blockIdx.x*64 + wv*16 + (lane&15);
  if (arow >= N_NODES) arow = N_NODES-1;       // clamp reads; writes guarded below
  int kgrp = lane>>4;
  f32x4 acc[NT];
  #pragma unroll
  for (int nt=0;nt<NT;nt++) acc[nt]=(f32x4){0.f,0.f,0.f,0.f};
  const unsigned short* aptr = h1b + (size_t)arow*HD + kgrp*8;
  #pragma unroll
  for (int ks=0; ks<8; ks++){
    bf16x8 a = *(const bf16x8*)(aptr + ks*32);
    #pragma unroll
    for (int nt=0; nt<NT; nt++){
      bf16x8 b = *(const bf16x8*)(Wp + (((ks*NT+nt)*64+lane)<<3));
      acc[nt] = __builtin_amdgcn_mfma_f32_16x16x32_bf16(a, b, acc[nt], 0, 0, 0);
    }
  }
  int rbase = blockIdx.x*64 + wv*16 + (lane>>4)*4;
  int col = lane&15;
  #pragma unroll
  for (int nt=0;nt<16;nt++){
    #pragma unroll
    for (int r=0;r<4;r++){
      int row = rbase+r;
      if (row<N_NODES) featb[(size_t)row*HD + nt*16+col] = f2b(acc[nt][r]);
    }
  }
  #pragma unroll
  for (int r=0;r<4;r++){
    int row = rbase+r;
    if (row<N_NODES) elr1[(size_t)row*16 + col] = acc[16][r];
  }
}

// ---------------- layer-1 edge softmax + aggregate + head-mean (bf16 gather, 16B/lane) ----------------

__global__ __launch_bounds__(256) void k_agg1(const int* __restrict__ offs, const int* __restrict__ csr_src,
   const int* __restrict__ csr_eid, const unsigned short* __restrict__ featb, const float* __restrict__ elr,
   const float* __restrict__ bias, float* __restrict__ out, float* __restrict__ alpha_out){
  __shared__ float s_al[4][ECAP][H_];
  __shared__ int   s_sn[4][ECAP];
  __shared__ int   s_eid[4][ECAP];
  __shared__ float s_m[4][H_], s_is[4][H_];
  int w = threadIdx.x>>6, lane = threadIdx.x&63;
  int n = blockIdx.x*4 + w;
  int h = lane>>3, sub = lane&7;
  int off = offs[n], deg = offs[n+1]-off;
  float er_n = elr[n*16 + 8 + h];

  float m=-1e30f, s=0.f;
  for (int i=sub; i<deg; i+=8){
    int p = off+i;
    int sn = csr_src[p];
    float sc = elr[sn*16+h] + er_n;
    sc = sc>0.f? sc : 0.2f*sc;
    if (i<ECAP){
      s_al[w][i][h]=sc;
      if (h==0){ s_sn[w][i]=sn; s_eid[w][i]=csr_eid[p]; }
    }
    float mn = fmaxf(m,sc);
    s = s*__expf(m-mn) + __expf(sc-mn);
    m = mn;
  }
  #pragma unroll
  for (int o=4;o>=1;o>>=1){
    float m2=__shfl_xor(m,o,64), s2=__shfl_xor(s,o,64);
    float mn=fmaxf(m,m2);
    s = s*__expf(m-mn) + s2*__expf(m2-mn);
    m = mn;
  }
  float inv_s = (s>0.f)? 1.f/s : 0.f;
  if (sub==0){ s_m[w][h]=m; s_is[w][h]=inv_s; }
  int dcap = deg<ECAP? deg:ECAP;
  __syncthreads();
  for (int i=sub; i<dcap; i+=8){
    float a = __expf(s_al[w][i][h]-m)*inv_s;
    s_al[w][i][h] = a;
    alpha_out[(size_t)s_eid[w][i]*H_ + h] = a;
  }
  __syncthreads();

  // ---- phase B ----
  int hw = lane>>5, dl = lane&31;
  int c0 = dl*8;               // global cols c0..c0+7
  int hd = dl>>2;              // head of these cols
  float acc[8] = {0,0,0,0,0,0,0,0};
  float acc2[8] = {0,0,0,0,0,0,0,0};
  int i = hw;
  for (; i+8<=dcap; i+=8){
    int sn0=s_sn[w][i], sn1=s_sn[w][i+2], sn2=s_sn[w][i+4], sn3=s_sn[w][i+6];
    float a0=s_al[w][i  ][hd];
    float a1=s_al[w][i+2][hd];
    float a2=s_al[w][i+4][hd];
    float a3=s_al[w][i+6][hd];
    u16x8 u0=*(const u16x8*)&featb[(size_t)sn0*HD+c0];
    u16x8 u1=*(const u16x8*)&featb[(size_t)sn1*HD+c0];
    u16x8 u2=*(const u16x8*)&featb[(size_t)sn2*HD+c0];
    u16x8 u3=*(const u16x8*)&featb[(size_t)sn3*HD+c0];
    #pragma unroll
    for (int q=0;q<8;q++){
      acc[q] =fmaf(a0,b2f(u0[q]),acc[q]);
      acc2[q]=fmaf(a1,b2f(u1[q]),acc2[q]);
      acc[q] =fmaf(a2,b2f(u2[q]),acc[q]);
      acc2[q]=fmaf(a3,b2f(u3[q]),acc2[q]);
    }
  }
  for (; i<dcap; i+=2){
    int sn = s_sn[w][i];
    float a=s_al[w][i][hd];
    u16x8 u=*(const u16x8*)&featb[(size_t)sn*HD+c0];
    #pragma unroll
    for (int q=0;q<8;q++) acc[q]=fmaf(a,b2f(u[q]),acc[q]);
  }
  for (; i<deg; i+=2){           // rare tail: deg > ECAP
    int p = off+i;
    int sn = csr_src[p];
    float sc = elr[sn*16+hd] + elr[n*16+8+hd];
    sc = sc>0.f? sc : 0.2f*sc;
    float a=__expf(sc-s_m[w][hd])*s_is[w][hd];
    u16x8 u=*(const u16x8*)&featb[(size_t)sn*HD+c0];
    #pragma unroll
    for (int q=0;q<8;q++) acc[q]=fmaf(a,b2f(u[q]),acc[q]);
    if ((dl&3)==0) alpha_out[(size_t)csr_eid[p]*H_+hd]=a;
  }

  // combine hw halves, add bias, mean over heads
  #pragma unroll
  for (int q=0;q<8;q++){
    acc[q]+=acc2[q];
    acc[q]+=__shfl_xor(acc[q],32,64);
    acc[q]+=bias[c0+q];
  }
  #pragma unroll
  for (int o=4;o<32;o<<=1){
    #pragma unroll
    for (int q=0;q<8;q++) acc[q]+=__shfl_xor(acc[q],o,64);
  }
  if (hw==0 && dl<4){
    float4 o0 = make_float4(acc[0],acc[1],acc[2],acc[3]);
    float4 o1 = make_float4(acc[4],acc[5],acc[6],acc[7]);
    o0.x*=0.125f; o0.y*=0.125f; o0.z*=0.125f; o0.w*=0.125f;
    o1.x*=0.125f; o1.y*=0.125f; o1.z*=0.125f; o1.w*=0.125f;
    *(float4*)&out[(size_t)n*D_ + dl*8    ] = o0;
    *(float4*)&out[(size_t)n*D_ + dl*8 + 4] = o1;
  }
}

// ---------------- launcher ----------------

extern "C" void kernel_launch(void* const* d_in, const int* in_sizes, int n_in,
                              void* d_out, int out_size, void* d_ws, size_t ws_size,
                              hipStream_t stream){
  const float* h   = (const float*)d_in[0];
  const int*   src = (const int*)d_in[1];
  const int*   dst = (const int*)d_in[2];
  const float* W0  = (const float*)d_in[3];
  const float* al0 = (const float*)d_in[4];
  const float* ar0 = (const float*)d_in[5];
  const float* b0  = (const float*)d_in[6];
  const float* W1  = (const float*)d_in[7];
  const float* al1 = (const float*)d_in[8];
  const float* ar1 = (const float*)d_in[9];
  const float* b1  = (const float*)d_in[10];
  float* out_final = (float*)d_out;
  float* alpha_out = (float*)d_out + (size_t)N_NODES*D_;

  char* wsp = (char*)d_ws;
  auto alloc=[&](size_t bytes)->char*{ char* p=wsp; wsp += (bytes+255)&~size_t(255); return p; };
  int*   deg     = (int*)alloc((size_t)N_NODES*4);
  int*   offs    = (int*)alloc((size_t)(N_NODES+1)*4);
  int*   cursor  = (int*)alloc((size_t)N_NODES*4);
  int*   bsums   = (int*)alloc(1024);
  int*   csr_src = (int*)alloc((size_t)N_EDGES*4);
  int*   csr_eid = (int*)alloc((size_t)N_EDGES*4);
  unsigned short* featb = (unsigned short*)alloc((size_t)N_NODES*HD*2);
  unsigned short* h1b   = (unsigned short*)alloc((size_t)N_NODES*HD*2);
  float* elr0    = (float*)alloc((size_t)N_NODES*16*4);
  float* elr1    = (float*)alloc((size_t)N_NODES*16*4);
  float* Wa0     = (float*)alloc((size_t)IN_DIM*16*4);
  float* Wa1     = (float*)alloc((size_t)HD*16*4);
  unsigned short* Wp  = (unsigned short*)alloc((size_t)8*NT*64*8*2);
  unsigned short* W0t = (unsigned short*)alloc((size_t)8192*2);

  hipMemsetAsync(deg, 0, (size_t)N_NODES*4, stream);
  int eb = (N_EDGES+255)/256;
  int nbchunks = (N_NODES+255)/256;
  k_hist       <<<eb,      256,0,stream>>>(dst, deg);
  k_block_sums <<<nbchunks,256,0,stream>>>(deg, bsums);
  k_scan_bsums <<<1,       64, 0,stream>>>(bsums, nbchunks);
  k_scan_chunks<<<nbchunks,256,0,stream>>>(deg, bsums, offs, cursor);
  k_scatter    <<<eb,      256,0,stream>>>(src, dst, cursor, csr_src, csr_eid);

  k_prep<IN_DIM><<<1,256,0,stream>>>(W0, al0, ar0, Wa0);
  k_prep<HD>    <<<8,256,0,stream>>>(W1, al1, ar1, Wa1);
  k_pack_w      <<<(8*NT*64*8+255)/256,256,0,stream>>>(W1, Wa1, Wp);
  k_pack_w0     <<<32,256,0,stream>>>(W0, W0t);

  k_el<IN_DIM><<<N_NODES/16,256,0,stream>>>(h, Wa0, elr0);
  k_agg0f     <<<N_NODES/4, 256,0,stream>>>(offs, csr_src, h, elr0, W0t, b0, h1b);
  k_gemm1_mfma<<<(N_NODES+63)/64,256,0,stream>>>(h1b, Wp, featb, elr1);
  k_agg1      <<<N_NODES/4, 256,0,stream>>>(offs, csr_src, csr_eid, featb, elr1, b1, out_final, alpha_out);
}

// Round 8
// 322.097 us; speedup vs baseline: 2.6085x; 1.0198x over previous
//
#include <hip/hip_runtime.h>

#define N_NODES 50000
#define N_EDGES 800000
#define IN_DIM 32
#define HD 256   // H*D
#define H_ 8
#define D_ 32
#define ECAP 64  // edges stashed in LDS per node (recompute tail beyond)
#define NT 17    // 16 W1 col-tiles + 1 Wa1 tile (el/er)

typedef __attribute__((ext_vector_type(8))) short bf16x8;
typedef __attribute__((ext_vector_type(4))) float f32x4;
typedef __attribute__((ext_vector_type(8))) unsigned short u16x8;

__device__ inline unsigned short f2b(float f){
  union{float f;unsigned int u;}v; v.f=f;
  unsigned int r=(v.u + 0x7FFFu + ((v.u>>16)&1u))>>16;
  return (unsigned short)r;
}
__device__ inline float b2f(unsigned short u){
  union{float f;unsigned int u32;}v; v.u32=((unsigned int)u)<<16; return v.f;
}

// ---------------- CSR build ----------------

__global__ void k_hist(const int* __restrict__ dst, int* __restrict__ deg){
  int e = blockIdx.x*256+threadIdx.x;
  if (e < N_EDGES) atomicAdd(&deg[dst[e]], 1);
}

__global__ void k_block_sums(const int* __restrict__ deg, int* __restrict__ bsums){
  int i = blockIdx.x*256+threadIdx.x;
  int v = (i<N_NODES)? deg[i]:0;
  #pragma unroll
  for (int o=32;o>=1;o>>=1) v += __shfl_xor(v,o,64);
  __shared__ int ws[4];
  if ((threadIdx.x&63)==0) ws[threadIdx.x>>6]=v;
  __syncthreads();
  if (threadIdx.x==0) bsums[blockIdx.x]=ws[0]+ws[1]+ws[2]+ws[3];
}

__global__ void k_scan_bsums(int* bsums, int nb){
  if (threadIdx.x==0 && blockIdx.x==0){
    int a=0;
    for (int i=0;i<nb;i++){int t=bsums[i]; bsums[i]=a; a+=t;}
  }
}

__device__ inline int wave_incl_scan(int v){
  int lane = threadIdx.x & 63;
  #pragma unroll
  for (int o=1;o<64;o<<=1){
    int t = __shfl_up(v,o,64);
    if (lane>=o) v+=t;
  }
  return v;
}

__global__ void k_scan_chunks(const int* __restrict__ deg, const int* __restrict__ bsums,
                              int* __restrict__ offs, int* __restrict__ cursor){
  int i = blockIdx.x*256+threadIdx.x;
  int v = (i<N_NODES)? deg[i]:0;
  int incl = wave_incl_scan(v);
  __shared__ int ws[4];
  int wid=threadIdx.x>>6, lane=threadIdx.x&63;
  if (lane==63) ws[wid]=incl;
  __syncthreads();
  if (threadIdx.x==0){int a=0; for(int w=0;w<4;w++){int t=ws[w];ws[w]=a;a+=t;}}
  __syncthreads();
  int excl = incl - v + ws[wid] + bsums[blockIdx.x];
  if (i<N_NODES){ offs[i]=excl; cursor[i]=excl; }
  if (i==N_NODES-1) offs[N_NODES]=excl+v;
}

__global__ void k_scatter(const int* __restrict__ src, const int* __restrict__ dst,
                          int* __restrict__ cursor, int* __restrict__ csr_src,
                          int* __restrict__ csr_eid){
  int e = blockIdx.x*256+threadIdx.x;
  if (e<N_EDGES){
    int d = dst[e];
    int pos = atomicAdd(&cursor[d],1);
    csr_src[pos]=src[e];
    csr_eid[pos]=e;
  }
}

// ---------------- Wa precompute ----------------

template<int K>
__global__ void k_prep(const float* __restrict__ W, const float* __restrict__ al,
                       const float* __restrict__ ar, float* __restrict__ Wa){
  int t = blockIdx.x*256 + threadIdx.x;
  int k = t>>3, hh = t&7;
  if (k < K){
    float sl=0.f, sr=0.f;
    #pragma unroll
    for (int d=0; d<32; d++){
      float w = W[(size_t)k*HD + hh*32 + d];
      sl = fmaf(w, al[hh*32+d], sl);
      sr = fmaf(w, ar[hh*32+d], sr);
    }
    Wa[k*16 + hh]     = sl;
    Wa[k*16 + 8 + hh] = sr;
  }
}

// ---------------- fragment pack: 16 tiles of W1 + 1 tile of Wa1 ----------------

__global__ void k_pack_w(const float* __restrict__ W, const float* __restrict__ Wa1,
                         unsigned short* __restrict__ Wp){
  int t = blockIdx.x*256+threadIdx.x;   // 8*NT*64*8 = 69632 total
  if (t >= 8*NT*64*8) return;
  int j=t&7, lane=(t>>3)&63;
  int g=t>>9; int nt=g%NT, ks=g/NT;
  int k = ks*32 + (lane>>4)*8 + j;
  float v;
  if (nt<16) v = W[(size_t)k*HD + nt*16 + (lane&15)];
  else       v = Wa1[k*16 + (lane&15)];
  Wp[t] = f2b(v);
}

// ---------------- W0 pack (bf16, k-major per col) ----------------

__global__ void k_pack_w0(const float* __restrict__ W0, unsigned short* __restrict__ W0t){
  int t = blockIdx.x*256+threadIdx.x;   // 8192 total
  if (t < 8192){
    int q = t&7, c = (t>>3)&255, kb = t>>11;
    W0t[t] = f2b(W0[(size_t)(kb*8+q)*HD + c]);
  }
}

// ---------------- el/er (layer 0, f32 input K=32) ----------------

template<int K>
__global__ __launch_bounds__(256) void k_el(const float* __restrict__ x, const float* __restrict__ Wa,
                                            float* __restrict__ elr){
  __shared__ float sWa[K*16];
  __shared__ float sx[16][K+1];
  int tid = threadIdx.x;
  int nb = blockIdx.x*16;
  for (int i = tid; i < K*16; i += 256) sWa[i] = Wa[i];
  for (int i = tid; i < 16*K; i += 256){
    int r = i / K, c = i % K;
    sx[r][c] = x[(size_t)(nb+r)*K + c];
  }
  __syncthreads();
  int node = tid>>4, j = tid&15;
  float s = 0.f;
  #pragma unroll 8
  for (int k=0;k<K;k++) s = fmaf(sx[node][k], sWa[k*16+j], s);
  elr[(size_t)(nb+node)*16 + j] = s;
}

// ---------------- FUSED layer-0 ----------------

__global__ __launch_bounds__(256) void k_agg0f(const int* __restrict__ offs, const int* __restrict__ csr_src,
    const float* __restrict__ x, const float* __restrict__ elr,
    const unsigned short* __restrict__ W0t, const float* __restrict__ b0,
    unsigned short* __restrict__ h1b){
  __shared__ float s_al[4][ECAP][H_];
  __shared__ int   s_sn[4][ECAP];
  __shared__ float s_m[4][H_], s_is[4][H_];
  __shared__ float s_hg[4][32*9];      // transposed hagg, stride 9 (bank-spread)
  int w = threadIdx.x>>6, lane = threadIdx.x&63;
  int n = blockIdx.x*4 + w;
  int h = lane>>3, sub = lane&7;
  int off = offs[n], deg = offs[n+1]-off;
  float er_n = elr[n*16 + 8 + h];

  // ---- phase A: scores -> LDS, online (m,s) ----
  float m=-1e30f, s=0.f;
  for (int i=sub; i<deg; i+=8){
    int sn = csr_src[off+i];
    float sc = elr[sn*16+h] + er_n;
    sc = sc>0.f? sc : 0.2f*sc;
    if (i<ECAP){ s_al[w][i][h] = sc; if (h==0) s_sn[w][i] = sn; }
    float mn = fmaxf(m,sc);
    s = s*__expf(m-mn) + __expf(sc-mn);
    m = mn;
  }
  #pragma unroll
  for (int o=4;o>=1;o>>=1){
    float m2=__shfl_xor(m,o,64), s2=__shfl_xor(s,o,64);
    float mn=fmaxf(m,m2);
    s = s*__expf(m-mn)+s2*__expf(m2-mn); m=mn;
  }
  float inv_s = (s>0.f)?1.f/s:0.f;
  if (sub==0){ s_m[w][h]=m; s_is[w][h]=inv_s; }
  int dcap = deg<ECAP? deg:ECAP;
  int dcap_pad = (dcap+7)&~7;
  for (int i=sub; i<dcap; i+=8)
    s_al[w][i][h] = __expf(s_al[w][i][h]-m)*inv_s;
  for (int i=dcap+lane; i<dcap_pad; i+=64){   // pad to 8-boundary: zero-alpha dummy edges
    s_sn[w][i]=0;
    *(float4*)&s_al[w][i][0]=make_float4(0,0,0,0);
    *(float4*)&s_al[w][i][4]=make_float4(0,0,0,0);
  }
  __syncthreads();

  // ---- phase B: tail-free 8-edge chunks (2 halves x 4-deep) ----
  int hw = lane>>5, d = lane&31;
  float acc[H_]  = {0,0,0,0,0,0,0,0};
  float accB[H_] = {0,0,0,0,0,0,0,0};
  int i = hw;
  for (; i<dcap_pad; i+=8){
    int snA = s_sn[w][i],   snB = s_sn[w][i+2];
    int snC = s_sn[w][i+4], snD = s_sn[w][i+6];
    float xvA = x[(size_t)snA*IN_DIM + d];
    float xvB = x[(size_t)snB*IN_DIM + d];
    float xvC = x[(size_t)snC*IN_DIM + d];
    float xvD = x[(size_t)snD*IN_DIM + d];
    float4 aA0 = *(const float4*)&s_al[w][i][0],   aA1 = *(const float4*)&s_al[w][i][4];
    float4 aB0 = *(const float4*)&s_al[w][i+2][0], aB1 = *(const float4*)&s_al[w][i+2][4];
    float4 aC0 = *(const float4*)&s_al[w][i+4][0], aC1 = *(const float4*)&s_al[w][i+4][4];
    float4 aD0 = *(const float4*)&s_al[w][i+6][0], aD1 = *(const float4*)&s_al[w][i+6][4];
    acc[0]=fmaf(aA0.x,xvA,acc[0]); acc[1]=fmaf(aA0.y,xvA,acc[1]);
    acc[2]=fmaf(aA0.z,xvA,acc[2]); acc[3]=fmaf(aA0.w,xvA,acc[3]);
    acc[4]=fmaf(aA1.x,xvA,acc[4]); acc[5]=fmaf(aA1.y,xvA,acc[5]);
    acc[6]=fmaf(aA1.z,xvA,acc[6]); acc[7]=fmaf(aA1.w,xvA,acc[7]);
    accB[0]=fmaf(aB0.x,xvB,accB[0]); accB[1]=fmaf(aB0.y,xvB,accB[1]);
    accB[2]=fmaf(aB0.z,xvB,accB[2]); accB[3]=fmaf(aB0.w,xvB,accB[3]);
    accB[4]=fmaf(aB1.x,xvB,accB[4]); accB[5]=fmaf(aB1.y,xvB,accB[5]);
    accB[6]=fmaf(aB1.z,xvB,accB[6]); accB[7]=fmaf(aB1.w,xvB,accB[7]);
    acc[0]=fmaf(aC0.x,xvC,acc[0]); acc[1]=fmaf(aC0.y,xvC,acc[1]);
    acc[2]=fmaf(aC0.z,xvC,acc[2]); acc[3]=fmaf(aC0.w,xvC,acc[3]);
    acc[4]=fmaf(aC1.x,xvC,acc[4]); acc[5]=fmaf(aC1.y,xvC,acc[5]);
    acc[6]=fmaf(aC1.z,xvC,acc[6]); acc[7]=fmaf(aC1.w,xvC,acc[7]);
    accB[0]=fmaf(aD0.x,xvD,accB[0]); accB[1]=fmaf(aD0.y,xvD,accB[1]);
    accB[2]=fmaf(aD0.z,xvD,accB[2]); accB[3]=fmaf(aD0.w,xvD,accB[3]);
    accB[4]=fmaf(aD1.x,xvD,accB[4]); accB[5]=fmaf(aD1.y,xvD,accB[5]);
    accB[6]=fmaf(aD1.z,xvD,accB[6]); accB[7]=fmaf(aD1.w,xvD,accB[7]);
  }
  for (; i<deg; i+=2){                    // rare tail: deg > ECAP, recompute
    int sn = csr_src[off+i];
    float xv = x[(size_t)sn*IN_DIM + d];
    #pragma unroll
    for (int hh=0;hh<H_;hh++){
      float sc = elr[sn*16+hh] + elr[n*16+8+hh];
      sc = sc>0.f? sc : 0.2f*sc;
      float a = __expf(sc - s_m[w][hh]) * s_is[w][hh];
      acc[hh]=fmaf(a,xv,acc[hh]);
    }
  }
  #pragma unroll
  for (int hh=0;hh<H_;hh++){
    acc[hh] += accB[hh];
    acc[hh] += __shfl_xor(acc[hh],32,64);
  }
  if (hw==0){
    #pragma unroll
    for (int hh=0;hh<H_;hh++) s_hg[w][d*9+hh] = acc[hh];
  }
  __syncthreads();

  // ---- epilogue (column-split): wave w computes cols [w*64, w*64+64) for ALL 4 nodes ----
  int col = w*64 + lane;
  int hcol = col>>5;
  float a0=0.f, a1=0.f, a2=0.f, a3=0.f;
  #pragma unroll
  for (int kb=0;kb<4;kb++){
    u16x8 wv8 = *(const u16x8*)(W0t + ((size_t)(kb*HD + col)<<3));
    #pragma unroll
    for (int q=0;q<8;q++){
      float wv = b2f(wv8[q]);
      int k = kb*8+q;
      a0 = fmaf(s_hg[0][k*9+hcol], wv, a0);
      a1 = fmaf(s_hg[1][k*9+hcol], wv, a1);
      a2 = fmaf(s_hg[2][k*9+hcol], wv, a2);
      a3 = fmaf(s_hg[3][k*9+hcol], wv, a3);
    }
  }
  float bb = b0[col];
  int n0 = blockIdx.x*4;
  h1b[(size_t)(n0+0)*HD+col] = f2b(fmaxf(a0+bb,0.f));
  h1b[(size_t)(n0+1)*HD+col] = f2b(fmaxf(a1+bb,0.f));
  h1b[(size_t)(n0+2)*HD+col] = f2b(fmaxf(a2+bb,0.f));
  h1b[(size_t)(n0+3)*HD+col] = f2b(fmaxf(a3+bb,0.f));
}

// ---------------- feat1 = h1b @ [W1 | Wa1] via MFMA; 32 rows/wave (B-frag reuse x2) ----------------

__global__ __launch_bounds__(256) void k_gemm1_mfma(const unsigned short* __restrict__ h1b,
    const unsigned short* __restrict__ Wp, unsigned short* __restrict__ featb,
    float* __restrict__ elr1){
  int wv = threadIdx.x>>6, lane = threadIdx.x&63;
  int rb = blockIdx.x*128 + wv*32;
  int ar0 = rb + (lane&15);
  int ar1 = ar0 + 16;
  if (ar0 >= N_NODES) ar0 = N_NODES-1;   // clamp reads; writes guarded below
  if (ar1 >= N_NODES) ar1 = N_NODES-1;
  int kgrp = lane>>4;
  f32x4 acc0[NT], acc1[NT];
  #pragma unroll
  for (int nt=0;nt<NT;nt++){ acc0[nt]=(f32x4){0.f,0.f,0.f,0.f}; acc1[nt]=(f32x4){0.f,0.f,0.f,0.f}; }
  const unsigned short* ap0 = h1b + (size_t)ar0*HD + kgrp*8;
  const unsigned short* ap1 = h1b + (size_t)ar1*HD + kgrp*8;
  #pragma unroll
  for (int ks=0; ks<8; ks++){
    bf16x8 a0 = *(const bf16x8*)(ap0 + ks*32);
    bf16x8 a1 = *(const bf16x8*)(ap1 + ks*32);
    #pragma unroll
    for (int nt=0; nt<NT; nt++){
      bf16x8 b = *(const bf16x8*)(Wp + (((ks*NT+nt)*64+lane)<<3));
      acc0[nt] = __builtin_amdgcn_mfma_f32_16x16x32_bf16(a0, b, acc0[nt], 0, 0, 0);
      acc1[nt] = __builtin_amdgcn_mfma_f32_16x16x32_bf16(a1, b, acc1[nt], 0, 0, 0);
    }
  }
  int col = lane&15;
  int rb0 = rb + (lane>>4)*4;
  int rb1 = rb0 + 16;
  #pragma unroll
  for (int nt=0;nt<16;nt++){
    #pragma unroll
    for (int r=0;r<4;r++){
      int row0 = rb0+r, row1 = rb1+r;
      if (row0<N_NODES) featb[(size_t)row0*HD + nt*16+col] = f2b(acc0[nt][r]);
      if (row1<N_NODES) featb[(size_t)row1*HD + nt*16+col] = f2b(acc1[nt][r]);
    }
  }
  #pragma unroll
  for (int r=0;r<4;r++){
    int row0 = rb0+r, row1 = rb1+r;
    if (row0<N_NODES) elr1[(size_t)row0*16 + col] = acc0[16][r];
    if (row1<N_NODES) elr1[(size_t)row1*16 + col] = acc1[16][r];
  }
}

// ---------------- layer-1 edge softmax + aggregate + head-mean ----------------

__global__ __launch_bounds__(256) void k_agg1(const int* __restrict__ offs, const int* __restrict__ csr_src,
   const int* __restrict__ csr_eid, const unsigned short* __restrict__ featb, const float* __restrict__ elr,
   const float* __restrict__ bias, float* __restrict__ out, float* __restrict__ alpha_out){
  __shared__ float s_al[4][ECAP][H_];
  __shared__ int   s_sn[4][ECAP];
  __shared__ int   s_eid[4][ECAP];
  __shared__ float s_m[4][H_], s_is[4][H_];
  int w = threadIdx.x>>6, lane = threadIdx.x&63;
  int n = blockIdx.x*4 + w;
  int h = lane>>3, sub = lane&7;
  int off = offs[n], deg = offs[n+1]-off;
  float er_n = elr[n*16 + 8 + h];

  float m=-1e30f, s=0.f;
  for (int i=sub; i<deg; i+=8){
    int p = off+i;
    int sn = csr_src[p];
    float sc = elr[sn*16+h] + er_n;
    sc = sc>0.f? sc : 0.2f*sc;
    if (i<ECAP){
      s_al[w][i][h]=sc;
      if (h==0){ s_sn[w][i]=sn; s_eid[w][i]=csr_eid[p]; }
    }
    float mn = fmaxf(m,sc);
    s = s*__expf(m-mn) + __expf(sc-mn);
    m = mn;
  }
  #pragma unroll
  for (int o=4;o>=1;o>>=1){
    float m2=__shfl_xor(m,o,64), s2=__shfl_xor(s,o,64);
    float mn=fmaxf(m,m2);
    s = s*__expf(m-mn) + s2*__expf(m2-mn);
    m = mn;
  }
  float inv_s = (s>0.f)? 1.f/s : 0.f;
  if (sub==0){ s_m[w][h]=m; s_is[w][h]=inv_s; }
  int dcap = deg<ECAP? deg:ECAP;
  int dcap_pad = (dcap+7)&~7;
  __syncthreads();   // s_eid ready before conversion pass writes alpha
  for (int i=sub; i<dcap; i+=8){
    float a = __expf(s_al[w][i][h]-m)*inv_s;
    s_al[w][i][h] = a;
    alpha_out[(size_t)s_eid[w][i]*H_ + h] = a;
  }
  for (int i=dcap+lane; i<dcap_pad; i+=64){   // pad to 8-boundary: zero-alpha dummy edges
    s_sn[w][i]=0;
    *(float4*)&s_al[w][i][0]=make_float4(0,0,0,0);
    *(float4*)&s_al[w][i][4]=make_float4(0,0,0,0);
  }
  __syncthreads();

  // ---- phase B: tail-free 8-edge chunks ----
  int hw = lane>>5, dl = lane&31;
  int c0 = dl*8;               // global cols c0..c0+7
  int hd = dl>>2;              // head of these cols
  float acc[8] = {0,0,0,0,0,0,0,0};
  float acc2[8] = {0,0,0,0,0,0,0,0};
  int i = hw;
  for (; i<dcap_pad; i+=8){
    int sn0=s_sn[w][i], sn1=s_sn[w][i+2], sn2=s_sn[w][i+4], sn3=s_sn[w][i+6];
    float a0=s_al[w][i  ][hd];
    float a1=s_al[w][i+2][hd];
    float a2=s_al[w][i+4][hd];
    float a3=s_al[w][i+6][hd];
    u16x8 u0=*(const u16x8*)&featb[(size_t)sn0*HD+c0];
    u16x8 u1=*(const u16x8*)&featb[(size_t)sn1*HD+c0];
    u16x8 u2=*(const u16x8*)&featb[(size_t)sn2*HD+c0];
    u16x8 u3=*(const u16x8*)&featb[(size_t)sn3*HD+c0];
    #pragma unroll
    for (int q=0;q<8;q++){
      acc[q] =fmaf(a0,b2f(u0[q]),acc[q]);
      acc2[q]=fmaf(a1,b2f(u1[q]),acc2[q]);
      acc[q] =fmaf(a2,b2f(u2[q]),acc[q]);
      acc2[q]=fmaf(a3,b2f(u3[q]),acc2[q]);
    }
  }
  for (; i<deg; i+=2){           // rare tail: deg > ECAP
    int p = off+i;
    int sn = csr_src[p];
    float sc = elr[sn*16+hd] + elr[n*16+8+hd];
    sc = sc>0.f? sc : 0.2f*sc;
    float a=__expf(sc-s_m[w][hd])*s_is[w][hd];
    u16x8 u=*(const u16x8*)&featb[(size_t)sn*HD+c0];
    #pragma unroll
    for (int q=0;q<8;q++) acc[q]=fmaf(a,b2f(u[q]),acc[q]);
    if ((dl&3)==0) alpha_out[(size_t)csr_eid[p]*H_+hd]=a;
  }

  // combine hw halves, add bias, mean over heads
  #pragma unroll
  for (int q=0;q<8;q++){
    acc[q]+=acc2[q];
    acc[q]+=__shfl_xor(acc[q],32,64);
    acc[q]+=bias[c0+q];
  }
  #pragma unroll
  for (int o=4;o<32;o<<=1){
    #pragma unroll
    for (int q=0;q<8;q++) acc[q]+=__shfl_xor(acc[q],o,64);
  }
  if (hw==0 && dl<4){
    float4 o0 = make_float4(acc[0],acc[1],acc[2],acc[3]);
    float4 o1 = make_float4(acc[4],acc[5],acc[6],acc[7]);
    o0.x*=0.125f; o0.y*=0.125f; o0.z*=0.125f; o0.w*=0.125f;
    o1.x*=0.125f; o1.y*=0.125f; o1.z*=0.125f; o1.w*=0.125f;
    *(float4*)&out[(size_t)n*D_ + dl*8    ] = o0;
    *(float4*)&out[(size_t)n*D_ + dl*8 + 4] = o1;
  }
}

// ---------------- launcher ----------------

extern "C" void kernel_launch(void* const* d_in, const int* in_sizes, int n_in,
                              void* d_out, int out_size, void* d_ws, size_t ws_size,
                              hipStream_t stream){
  const float* h   = (const float*)d_in[0];
  const int*   src = (const int*)d_in[1];
  const int*   dst = (const int*)d_in[2];
  const float* W0  = (const float*)d_in[3];
  const float* al0 = (const float*)d_in[4];
  const float* ar0 = (const float*)d_in[5];
  const float* b0  = (const float*)d_in[6];
  const float* W1  = (const float*)d_in[7];
  const float* al1 = (const float*)d_in[8];
  const float* ar1 = (const float*)d_in[9];
  const float* b1  = (const float*)d_in[10];
  float* out_final = (float*)d_out;
  float* alpha_out = (float*)d_out + (size_t)N_NODES*D_;

  char* wsp = (char*)d_ws;
  auto alloc=[&](size_t bytes)->char*{ char* p=wsp; wsp += (bytes+255)&~size_t(255); return p; };
  int*   deg     = (int*)alloc((size_t)N_NODES*4);
  int*   offs    = (int*)alloc((size_t)(N_NODES+1)*4);
  int*   cursor  = (int*)alloc((size_t)N_NODES*4);
  int*   bsums   = (int*)alloc(1024);
  int*   csr_src = (int*)alloc((size_t)N_EDGES*4);
  int*   csr_eid = (int*)alloc((size_t)N_EDGES*4);
  unsigned short* featb = (unsigned short*)alloc((size_t)N_NODES*HD*2);
  unsigned short* h1b   = (unsigned short*)alloc((size_t)N_NODES*HD*2);
  float* elr0    = (float*)alloc((size_t)N_NODES*16*4);
  float* elr1    = (float*)alloc((size_t)N_NODES*16*4);
  float* Wa0     = (float*)alloc((size_t)IN_DIM*16*4);
  float* Wa1     = (float*)alloc((size_t)HD*16*4);
  unsigned short* Wp  = (unsigned short*)alloc((size_t)8*NT*64*8*2);
  unsigned short* W0t = (unsigned short*)alloc((size_t)8192*2);

  hipMemsetAsync(deg, 0, (size_t)N_NODES*4, stream);
  int eb = (N_EDGES+255)/256;
  int nbchunks = (N_NODES+255)/256;
  k_hist       <<<eb,      256,0,stream>>>(dst, deg);
  k_block_sums <<<nbchunks,256,0,stream>>>(deg, bsums);
  k_scan_bsums <<<1,       64, 0,stream>>>(bsums, nbchunks);
  k_scan_chunks<<<nbchunks,256,0,stream>>>(deg, bsums, offs, cursor);
  k_scatter    <<<eb,      256,0,stream>>>(src, dst, cursor, csr_src, csr_eid);

  k_prep<IN_DIM><<<1,256,0,stream>>>(W0, al0, ar0, Wa0);
  k_prep<HD>    <<<8,256,0,stream>>>(W1, al1, ar1, Wa1);
  k_pack_w      <<<(8*NT*64*8+255)/256,256,0,stream>>>(W1, Wa1, Wp);
  k_pack_w0     <<<32,256,0,stream>>>(W0, W0t);

  k_el<IN_DIM><<<N_NODES/16,256,0,stream>>>(h, Wa0, elr0);
  k_agg0f     <<<N_NODES/4, 256,0,stream>>>(offs, csr_src, h, elr0, W0t, b0, h1b);
  k_gemm1_mfma<<<(N_NODES+127)/128,256,0,stream>>>(h1b, Wp, featb, elr1);
  k_agg1      <<<N_NODES/4, 256,0,stream>>>(offs, csr_src, csr_eid, featb, elr1, b1, out_final, alpha_out);
}

// Round 9
// 315.910 us; speedup vs baseline: 2.6596x; 1.0196x over previous
//
#include <hip/hip_runtime.h>

#define N_NODES 50000
#define N_EDGES 800000
#define IN_DIM 32
#define HD 256   // H*D
#define H_ 8
#define D_ 32
#define ECAP 64  // edges stashed in LDS per node (recompute tail beyond)
#define NT 17    // 16 W1 col-tiles + 1 Wa1 tile (el/er)

typedef __attribute__((ext_vector_type(8))) short bf16x8;
typedef __attribute__((ext_vector_type(4))) float f32x4;
typedef __attribute__((ext_vector_type(8))) unsigned short u16x8;

__device__ inline unsigned short f2b(float f){
  union{float f;unsigned int u;}v; v.f=f;
  unsigned int r=(v.u + 0x7FFFu + ((v.u>>16)&1u))>>16;
  return (unsigned short)r;
}
__device__ inline float b2f(unsigned short u){
  union{float f;unsigned int u32;}v; v.u32=((unsigned int)u)<<16; return v.f;
}

// ---------------- CSR build ----------------

__global__ void k_hist(const int* __restrict__ dst, int* __restrict__ deg){
  int e = blockIdx.x*256+threadIdx.x;
  if (e < N_EDGES) atomicAdd(&deg[dst[e]], 1);
}

__global__ void k_block_sums(const int* __restrict__ deg, int* __restrict__ bsums){
  int i = blockIdx.x*256+threadIdx.x;
  int v = (i<N_NODES)? deg[i]:0;
  #pragma unroll
  for (int o=32;o>=1;o>>=1) v += __shfl_xor(v,o,64);
  __shared__ int ws[4];
  if ((threadIdx.x&63)==0) ws[threadIdx.x>>6]=v;
  __syncthreads();
  if (threadIdx.x==0) bsums[blockIdx.x]=ws[0]+ws[1]+ws[2]+ws[3];
}

__global__ void k_scan_bsums(int* bsums, int nb){
  if (threadIdx.x==0 && blockIdx.x==0){
    int a=0;
    for (int i=0;i<nb;i++){int t=bsums[i]; bsums[i]=a; a+=t;}
  }
}

__device__ inline int wave_incl_scan(int v){
  int lane = threadIdx.x & 63;
  #pragma unroll
  for (int o=1;o<64;o<<=1){
    int t = __shfl_up(v,o,64);
    if (lane>=o) v+=t;
  }
  return v;
}

__global__ void k_scan_chunks(const int* __restrict__ deg, const int* __restrict__ bsums,
                              int* __restrict__ offs, int* __restrict__ cursor){
  int i = blockIdx.x*256+threadIdx.x;
  int v = (i<N_NODES)? deg[i]:0;
  int incl = wave_incl_scan(v);
  __shared__ int ws[4];
  int wid=threadIdx.x>>6, lane=threadIdx.x&63;
  if (lane==63) ws[wid]=incl;
  __syncthreads();
  if (threadIdx.x==0){int a=0; for(int w=0;w<4;w++){int t=ws[w];ws[w]=a;a+=t;}}
  __syncthreads();
  int excl = incl - v + ws[wid] + bsums[blockIdx.x];
  if (i<N_NODES){ offs[i]=excl; cursor[i]=excl; }
  if (i==N_NODES-1) offs[N_NODES]=excl+v;
}

__global__ void k_scatter(const int* __restrict__ src, const int* __restrict__ dst,
                          int* __restrict__ cursor, int* __restrict__ csr_src,
                          int* __restrict__ csr_eid){
  int e = blockIdx.x*256+threadIdx.x;
  if (e<N_EDGES){
    int d = dst[e];
    int pos = atomicAdd(&cursor[d],1);
    csr_src[pos]=src[e];
    csr_eid[pos]=e;
  }
}

// ---------------- Wa precompute ----------------

template<int K>
__global__ void k_prep(const float* __restrict__ W, const float* __restrict__ al,
                       const float* __restrict__ ar, float* __restrict__ Wa){
  int t = blockIdx.x*256 + threadIdx.x;
  int k = t>>3, hh = t&7;
  if (k < K){
    float sl=0.f, sr=0.f;
    #pragma unroll
    for (int d=0; d<32; d++){
      float w = W[(size_t)k*HD + hh*32 + d];
      sl = fmaf(w, al[hh*32+d], sl);
      sr = fmaf(w, ar[hh*32+d], sr);
    }
    Wa[k*16 + hh]     = sl;
    Wa[k*16 + 8 + hh] = sr;
  }
}

// ---------------- fragment pack: 16 tiles of W1 + 1 tile of Wa1 ----------------

__global__ void k_pack_w(const float* __restrict__ W, const float* __restrict__ Wa1,
                         unsigned short* __restrict__ Wp){
  int t = blockIdx.x*256+threadIdx.x;   // 8*NT*64*8 = 69632 total
  if (t >= 8*NT*64*8) return;
  int j=t&7, lane=(t>>3)&63;
  int g=t>>9; int nt=g%NT, ks=g/NT;
  int k = ks*32 + (lane>>4)*8 + j;
  float v;
  if (nt<16) v = W[(size_t)k*HD + nt*16 + (lane&15)];
  else       v = Wa1[k*16 + (lane&15)];
  Wp[t] = f2b(v);
}

// ---------------- W0 pack (bf16, k-major per col) ----------------

__global__ void k_pack_w0(const float* __restrict__ W0, unsigned short* __restrict__ W0t){
  int t = blockIdx.x*256+threadIdx.x;   // 8192 total
  if (t < 8192){
    int q = t&7, c = (t>>3)&255, kb = t>>11;
    W0t[t] = f2b(W0[(size_t)(kb*8+q)*HD + c]);
  }
}

// ---------------- el/er (layer 0, f32 input K=32) ----------------

template<int K>
__global__ __launch_bounds__(256) void k_el(const float* __restrict__ x, const float* __restrict__ Wa,
                                            float* __restrict__ elr){
  __shared__ float sWa[K*16];
  __shared__ float sx[16][K+1];
  int tid = threadIdx.x;
  int nb = blockIdx.x*16;
  for (int i = tid; i < K*16; i += 256) sWa[i] = Wa[i];
  for (int i = tid; i < 16*K; i += 256){
    int r = i / K, c = i % K;
    sx[r][c] = x[(size_t)(nb+r)*K + c];
  }
  __syncthreads();
  int node = tid>>4, j = tid&15;
  float s = 0.f;
  #pragma unroll 8
  for (int k=0;k<K;k++) s = fmaf(sx[node][k], sWa[k*16+j], s);
  elr[(size_t)(nb+node)*16 + j] = s;
}

// ---------------- FUSED layer-0 ----------------

__global__ __launch_bounds__(256) void k_agg0f(const int* __restrict__ offs, const int* __restrict__ csr_src,
    const float* __restrict__ x, const float* __restrict__ elr,
    const unsigned short* __restrict__ W0t, const float* __restrict__ b0,
    unsigned short* __restrict__ h1b){
  __shared__ float s_al[4][ECAP][H_];
  __shared__ int   s_sn[4][ECAP];
  __shared__ float s_m[4][H_], s_is[4][H_];
  __shared__ float s_hg[4][32*9];      // transposed hagg, stride 9 (bank-spread)
  int w = threadIdx.x>>6, lane = threadIdx.x&63;
  int n = blockIdx.x*4 + w;
  int h = lane>>3, sub = lane&7;
  int off = offs[n], deg = offs[n+1]-off;
  float er_n = elr[n*16 + 8 + h];

  // ---- phase A: scores -> LDS, online (m,s) ----
  float m=-1e30f, s=0.f;
  for (int i=sub; i<deg; i+=8){
    int sn = csr_src[off+i];
    float sc = elr[sn*16+h] + er_n;
    sc = sc>0.f? sc : 0.2f*sc;
    if (i<ECAP){ s_al[w][i][h] = sc; if (h==0) s_sn[w][i] = sn; }
    float mn = fmaxf(m,sc);
    s = s*__expf(m-mn) + __expf(sc-mn);
    m = mn;
  }
  #pragma unroll
  for (int o=4;o>=1;o>>=1){
    float m2=__shfl_xor(m,o,64), s2=__shfl_xor(s,o,64);
    float mn=fmaxf(m,m2);
    s = s*__expf(m-mn)+s2*__expf(m2-mn); m=mn;
  }
  float inv_s = (s>0.f)?1.f/s:0.f;
  if (sub==0){ s_m[w][h]=m; s_is[w][h]=inv_s; }
  int dcap = deg<ECAP? deg:ECAP;
  int dcap_pad = (dcap+15)&~15;
  for (int i=sub; i<dcap; i+=8)
    s_al[w][i][h] = __expf(s_al[w][i][h]-m)*inv_s;
  for (int i=dcap+lane; i<dcap_pad; i+=64){   // pad to 16-boundary: zero-alpha dummy edges
    s_sn[w][i]=0;
    *(float4*)&s_al[w][i][0]=make_float4(0,0,0,0);
    *(float4*)&s_al[w][i][4]=make_float4(0,0,0,0);
  }
  __syncthreads();

  // ---- phase B: tail-free 16-edge chunks, 8 gathers in flight per half-wave ----
  int hw = lane>>5, d = lane&31;
  float acc[H_]  = {0,0,0,0,0,0,0,0};
  int i = hw;
  for (; i<dcap_pad; i+=16){
    float xv[8];
    #pragma unroll
    for (int q=0;q<8;q++)
      xv[q] = x[(size_t)s_sn[w][i+2*q]*IN_DIM + d];
    #pragma unroll
    for (int q=0;q<8;q++){
      float4 a0 = *(const float4*)&s_al[w][i+2*q][0];
      float4 a1 = *(const float4*)&s_al[w][i+2*q][4];
      acc[0]=fmaf(a0.x,xv[q],acc[0]); acc[1]=fmaf(a0.y,xv[q],acc[1]);
      acc[2]=fmaf(a0.z,xv[q],acc[2]); acc[3]=fmaf(a0.w,xv[q],acc[3]);
      acc[4]=fmaf(a1.x,xv[q],acc[4]); acc[5]=fmaf(a1.y,xv[q],acc[5]);
      acc[6]=fmaf(a1.z,xv[q],acc[6]); acc[7]=fmaf(a1.w,xv[q],acc[7]);
    }
  }
  for (; i<deg; i+=2){                    // rare tail: deg > ECAP, recompute
    int sn = csr_src[off+i];
    float xv = x[(size_t)sn*IN_DIM + d];
    #pragma unroll
    for (int hh=0;hh<H_;hh++){
      float sc = elr[sn*16+hh] + elr[n*16+8+hh];
      sc = sc>0.f? sc : 0.2f*sc;
      float a = __expf(sc - s_m[w][hh]) * s_is[w][hh];
      acc[hh]=fmaf(a,xv,acc[hh]);
    }
  }
  #pragma unroll
  for (int hh=0;hh<H_;hh++)
    acc[hh] += __shfl_xor(acc[hh],32,64);
  if (hw==0){
    #pragma unroll
    for (int hh=0;hh<H_;hh++) s_hg[w][d*9+hh] = acc[hh];
  }
  __syncthreads();

  // ---- epilogue (column-split): wave w computes cols [w*64, w*64+64) for ALL 4 nodes ----
  int col = w*64 + lane;
  int hcol = col>>5;
  float a0=0.f, a1=0.f, a2=0.f, a3=0.f;
  #pragma unroll
  for (int kb=0;kb<4;kb++){
    u16x8 wv8 = *(const u16x8*)(W0t + ((size_t)(kb*HD + col)<<3));
    #pragma unroll
    for (int q=0;q<8;q++){
      float wv = b2f(wv8[q]);
      int k = kb*8+q;
      a0 = fmaf(s_hg[0][k*9+hcol], wv, a0);
      a1 = fmaf(s_hg[1][k*9+hcol], wv, a1);
      a2 = fmaf(s_hg[2][k*9+hcol], wv, a2);
      a3 = fmaf(s_hg[3][k*9+hcol], wv, a3);
    }
  }
  float bb = b0[col];
  int n0 = blockIdx.x*4;
  h1b[(size_t)(n0+0)*HD+col] = f2b(fmaxf(a0+bb,0.f));
  h1b[(size_t)(n0+1)*HD+col] = f2b(fmaxf(a1+bb,0.f));
  h1b[(size_t)(n0+2)*HD+col] = f2b(fmaxf(a2+bb,0.f));
  h1b[(size_t)(n0+3)*HD+col] = f2b(fmaxf(a3+bb,0.f));
}

// ---------------- feat1 = h1b @ [W1 | Wa1] via MFMA; 32 rows/wave (B-frag reuse x2) ----------------

__global__ __launch_bounds__(256) void k_gemm1_mfma(const unsigned short* __restrict__ h1b,
    const unsigned short* __restrict__ Wp, unsigned short* __restrict__ featb,
    float* __restrict__ elr1){
  int wv = threadIdx.x>>6, lane = threadIdx.x&63;
  int rb = blockIdx.x*128 + wv*32;
  int ar0 = rb + (lane&15);
  int ar1 = ar0 + 16;
  if (ar0 >= N_NODES) ar0 = N_NODES-1;   // clamp reads; writes guarded below
  if (ar1 >= N_NODES) ar1 = N_NODES-1;
  int kgrp = lane>>4;
  f32x4 acc0[NT], acc1[NT];
  #pragma unroll
  for (int nt=0;nt<NT;nt++){ acc0[nt]=(f32x4){0.f,0.f,0.f,0.f}; acc1[nt]=(f32x4){0.f,0.f,0.f,0.f}; }
  const unsigned short* ap0 = h1b + (size_t)ar0*HD + kgrp*8;
  const unsigned short* ap1 = h1b + (size_t)ar1*HD + kgrp*8;
  #pragma unroll
  for (int ks=0; ks<8; ks++){
    bf16x8 a0 = *(const bf16x8*)(ap0 + ks*32);
    bf16x8 a1 = *(const bf16x8*)(ap1 + ks*32);
    #pragma unroll
    for (int nt=0; nt<NT; nt++){
      bf16x8 b = *(const bf16x8*)(Wp + (((ks*NT+nt)*64+lane)<<3));
      acc0[nt] = __builtin_amdgcn_mfma_f32_16x16x32_bf16(a0, b, acc0[nt], 0, 0, 0);
      acc1[nt] = __builtin_amdgcn_mfma_f32_16x16x32_bf16(a1, b, acc1[nt], 0, 0, 0);
    }
  }
  int col = lane&15;
  int rb0 = rb + (lane>>4)*4;
  int rb1 = rb0 + 16;
  #pragma unroll
  for (int nt=0;nt<16;nt++){
    #pragma unroll
    for (int r=0;r<4;r++){
      int row0 = rb0+r, row1 = rb1+r;
      if (row0<N_NODES) featb[(size_t)row0*HD + nt*16+col] = f2b(acc0[nt][r]);
      if (row1<N_NODES) featb[(size_t)row1*HD + nt*16+col] = f2b(acc1[nt][r]);
    }
  }
  #pragma unroll
  for (int r=0;r<4;r++){
    int row0 = rb0+r, row1 = rb1+r;
    if (row0<N_NODES) elr1[(size_t)row0*16 + col] = acc0[16][r];
    if (row1<N_NODES) elr1[(size_t)row1*16 + col] = acc1[16][r];
  }
}

// ---------------- layer-1 edge softmax + aggregate + head-mean ----------------
// phase A: (h=lane>>3, sub=lane&7). phase B: FULL WAVE per edge, lane -> cols lane*4..+3, head lane>>3.

__global__ __launch_bounds__(256) void k_agg1(const int* __restrict__ offs, const int* __restrict__ csr_src,
   const int* __restrict__ csr_eid, const unsigned short* __restrict__ featb, const float* __restrict__ elr,
   const float* __restrict__ bias, float* __restrict__ out, float* __restrict__ alpha_out){
  __shared__ float s_al[4][ECAP][H_];
  __shared__ int   s_sn[4][ECAP];
  __shared__ int   s_eid[4][ECAP];
  int w = threadIdx.x>>6, lane = threadIdx.x&63;
  int n = blockIdx.x*4 + w;
  int h = lane>>3, sub = lane&7;
  int off = offs[n], deg = offs[n+1]-off;
  float er_n = elr[n*16 + 8 + h];

  float m=-1e30f, s=0.f;
  for (int i=sub; i<deg; i+=8){
    int p = off+i;
    int sn = csr_src[p];
    float sc = elr[sn*16+h] + er_n;
    sc = sc>0.f? sc : 0.2f*sc;
    if (i<ECAP){
      s_al[w][i][h]=sc;
      if (h==0){ s_sn[w][i]=sn; s_eid[w][i]=csr_eid[p]; }
    }
    float mn = fmaxf(m,sc);
    s = s*__expf(m-mn) + __expf(sc-mn);
    m = mn;
  }
  #pragma unroll
  for (int o=4;o>=1;o>>=1){
    float m2=__shfl_xor(m,o,64), s2=__shfl_xor(s,o,64);
    float mn=fmaxf(m,m2);
    s = s*__expf(m-mn) + s2*__expf(m2-mn);
    m = mn;
  }
  float inv_s = (s>0.f)? 1.f/s : 0.f;
  int dcap = deg<ECAP? deg:ECAP;
  int dcap_pad = (dcap+7)&~7;
  __syncthreads();   // s_eid ready before conversion pass writes alpha
  for (int i=sub; i<dcap; i+=8){
    float a = __expf(s_al[w][i][h]-m)*inv_s;
    s_al[w][i][h] = a;
    alpha_out[(size_t)s_eid[w][i]*H_ + h] = a;
  }
  for (int i=dcap+lane; i<dcap_pad; i+=64){   // pad to 8-boundary: zero-alpha dummy edges
    s_sn[w][i]=0;
    *(float4*)&s_al[w][i][0]=make_float4(0,0,0,0);
    *(float4*)&s_al[w][i][4]=make_float4(0,0,0,0);
  }
  __syncthreads();

  // ---- phase B: full-wave per edge, 8 gathers in flight ----
  int c0 = lane*4;             // cols c0..c0+3 (head h == lane>>3)
  float acc[4] = {0,0,0,0};
  for (int i=0; i<dcap_pad; i+=8){
    float av[8]; ushort4 uu[8];
    #pragma unroll
    for (int q=0;q<8;q++){
      int sn = s_sn[w][i+q];
      av[q] = s_al[w][i+q][h];
      uu[q] = *(const ushort4*)&featb[(size_t)sn*HD + c0];
    }
    #pragma unroll
    for (int q=0;q<8;q++){
      acc[0]=fmaf(av[q],b2f(uu[q].x),acc[0]);
      acc[1]=fmaf(av[q],b2f(uu[q].y),acc[1]);
      acc[2]=fmaf(av[q],b2f(uu[q].z),acc[2]);
      acc[3]=fmaf(av[q],b2f(uu[q].w),acc[3]);
    }
  }
  for (int i=ECAP; i<deg; ++i){           // rare tail: deg > ECAP, full wave per edge
    int p = off+i;
    int sn = csr_src[p];
    float sc = elr[sn*16+h] + er_n;
    sc = sc>0.f? sc : 0.2f*sc;
    float a=__expf(sc-m)*inv_s;
    ushort4 u=*(const ushort4*)&featb[(size_t)sn*HD+c0];
    acc[0]=fmaf(a,b2f(u.x),acc[0]);
    acc[1]=fmaf(a,b2f(u.y),acc[1]);
    acc[2]=fmaf(a,b2f(u.z),acc[2]);
    acc[3]=fmaf(a,b2f(u.w),acc[3]);
    if (sub==0) alpha_out[(size_t)csr_eid[p]*H_+h]=a;
  }

  // bias, then mean over heads (sum lanes with same lane&7)
  #pragma unroll
  for (int q=0;q<4;q++) acc[q] += bias[c0+q];
  #pragma unroll
  for (int o=8;o<64;o<<=1){
    #pragma unroll
    for (int q=0;q<4;q++) acc[q]+=__shfl_xor(acc[q],o,64);
  }
  if (h==0){
    float4 o0 = make_float4(acc[0]*0.125f, acc[1]*0.125f, acc[2]*0.125f, acc[3]*0.125f);
    *(float4*)&out[(size_t)n*D_ + c0] = o0;
  }
}

// ---------------- launcher ----------------

extern "C" void kernel_launch(void* const* d_in, const int* in_sizes, int n_in,
                              void* d_out, int out_size, void* d_ws, size_t ws_size,
                              hipStream_t stream){
  const float* h   = (const float*)d_in[0];
  const int*   src = (const int*)d_in[1];
  const int*   dst = (const int*)d_in[2];
  const float* W0  = (const float*)d_in[3];
  const float* al0 = (const float*)d_in[4];
  const float* ar0 = (const float*)d_in[5];
  const float* b0  = (const float*)d_in[6];
  const float* W1  = (const float*)d_in[7];
  const float* al1 = (const float*)d_in[8];
  const float* ar1 = (const float*)d_in[9];
  const float* b1  = (const float*)d_in[10];
  float* out_final = (float*)d_out;
  float* alpha_out = (float*)d_out + (size_t)N_NODES*D_;

  char* wsp = (char*)d_ws;
  auto alloc=[&](size_t bytes)->char*{ char* p=wsp; wsp += (bytes+255)&~size_t(255); return p; };
  int*   deg     = (int*)alloc((size_t)N_NODES*4);
  int*   offs    = (int*)alloc((size_t)(N_NODES+1)*4);
  int*   cursor  = (int*)alloc((size_t)N_NODES*4);
  int*   bsums   = (int*)alloc(1024);
  int*   csr_src = (int*)alloc((size_t)N_EDGES*4);
  int*   csr_eid = (int*)alloc((size_t)N_EDGES*4);
  unsigned short* featb = (unsigned short*)alloc((size_t)N_NODES*HD*2);
  unsigned short* h1b   = (unsigned short*)alloc((size_t)N_NODES*HD*2);
  float* elr0    = (float*)alloc((size_t)N_NODES*16*4);
  float* elr1    = (float*)alloc((size_t)N_NODES*16*4);
  float* Wa0     = (float*)alloc((size_t)IN_DIM*16*4);
  float* Wa1     = (float*)alloc((size_t)HD*16*4);
  unsigned short* Wp  = (unsigned short*)alloc((size_t)8*NT*64*8*2);
  unsigned short* W0t = (unsigned short*)alloc((size_t)8192*2);

  hipMemsetAsync(deg, 0, (size_t)N_NODES*4, stream);
  int eb = (N_EDGES+255)/256;
  int nbchunks = (N_NODES+255)/256;
  k_hist       <<<eb,      256,0,stream>>>(dst, deg);
  k_block_sums <<<nbchunks,256,0,stream>>>(deg, bsums);
  k_scan_bsums <<<1,       64, 0,stream>>>(bsums, nbchunks);
  k_scan_chunks<<<nbchunks,256,0,stream>>>(deg, bsums, offs, cursor);
  k_scatter    <<<eb,      256,0,stream>>>(src, dst, cursor, csr_src, csr_eid);

  k_prep<IN_DIM><<<1,256,0,stream>>>(W0, al0, ar0, Wa0);
  k_prep<HD>    <<<8,256,0,stream>>>(W1, al1, ar1, Wa1);
  k_pack_w      <<<(8*NT*64*8+255)/256,256,0,stream>>>(W1, Wa1, Wp);
  k_pack_w0     <<<32,256,0,stream>>>(W0, W0t);

  k_el<IN_DIM><<<N_NODES/16,256,0,stream>>>(h, Wa0, elr0);
  k_agg0f     <<<N_NODES/4, 256,0,stream>>>(offs, csr_src, h, elr0, W0t, b0, h1b);
  k_gemm1_mfma<<<(N_NODES+127)/128,256,0,stream>>>(h1b, Wp, featb, elr1);
  k_agg1      <<<N_NODES/4, 256,0,stream>>>(offs, csr_src, csr_eid, featb, elr1, b1, out_final, alpha_out);
}